// Round 9
// baseline (5517.230 us; speedup 1.0000x reference)
//
#include <hip/hip_runtime.h>
#include <float.h>
#include <math.h>
#include <stdint.h>

// ---------------------------------------------------------------------------
// Model_33062658245168: Informer-style time-series model. fp32 in/out
// (runtime-detected; bf16 fallback kept). B=32 S=512 C=512 D=512 DF=2048 H=8
// E=64 P=16 PRED=96 K(topk)=10, N=16384.
//
// Round 9: gattn LDS-issue fix. q row hoisted to 16 float4 regs (kills 512
// scalar qs reads/wave), kt stride 65->68 so staging + score reads are b128
// (512 b32 -> 128 b128), ww A@V reads float4 (512 -> 128 broadcasts).
// Budgeted VGPR ~90 (c8 loop NOT unrolled) to avoid round-7's spill.
// ---------------------------------------------------------------------------

#define NB   32
#define SS   512
#define CC   512
#define DD   512
#define DFF  2048
#define HH   8
#define EE   64
#define PRED 96

typedef __attribute__((ext_vector_type(8))) short short8;
typedef __attribute__((ext_vector_type(4))) float f32x4;

__device__ __forceinline__ float b2f(ushort u) {
  union { float f; uint32_t i; } c; c.i = ((uint32_t)u) << 16; return c.f;
}
__device__ __forceinline__ ushort f2b(float f) {
  union { float f; uint32_t i; } c; c.f = f;
  uint32_t x = c.i;
  return (ushort)((x + 0x7fffu + ((x >> 16) & 1u)) >> 16);   // RNE
}
__device__ __forceinline__ float lin(const void* p, size_t i, int f32) {
  return f32 ? ((const float*)p)[i] : b2f(((const ushort*)p)[i]);
}

// ---------------- dtype detection (1 = fp32 inputs) ----------------
__global__ __launch_bounds__(256) void detect_dtype(
    const ushort* __restrict__ x, int* __restrict__ flag)
{
  __shared__ float red[256];
  const int t = threadIdx.x;
  float v = fabsf(b2f(x[2 * t]));
  if (!(v < 1e30f)) v = 1e30f;
  red[t] = v;
  __syncthreads();
  for (int off = 128; off > 0; off >>= 1) {
    if (t < off) red[t] = fmaxf(red[t], red[t + off]);
    __syncthreads();
  }
  if (t == 0) flag[0] = (red[0] > 1e6f) ? 1 : 0;
}

// ---------------- instance norm stats ----------------
__global__ __launch_bounds__(256) void instnorm_stats(
    const void* __restrict__ x, float* __restrict__ meanb, float* __restrict__ stdb,
    const int* __restrict__ dtf)
{
  const int f32 = *dtf;
  const int c = blockIdx.x * 256 + threadIdx.x;
  const int b = blockIdx.y;
  float s = 0.f, s2 = 0.f;
  for (int t = 0; t < SS; ++t) {
    const float xv = lin(x, ((size_t)(b * SS) + t) * CC + c, f32);
    s += xv; s2 += xv * xv;
  }
  const float mu  = s * (1.f / SS);
  const float var = s2 * (1.f / SS) - mu * mu;
  meanb[b * CC + c] = mu;
  stdb [b * CC + c] = sqrtf(var + 1e-5f);
}

// ---------------- normalize + transpose one chunk ----------------
__global__ __launch_bounds__(256) void norm_transpose(
    const void* __restrict__ x, const float* __restrict__ meanb,
    const float* __restrict__ stdb, float* __restrict__ xTc, int b_base,
    const int* __restrict__ dtf)
{
  const int f32 = *dtf;
  __shared__ float t[32][33];
  const int s0 = blockIdx.x * 32, c0 = blockIdx.y * 32, lb = blockIdx.z;
  const int b = b_base + lb;
  const int tx = threadIdx.x & 31, ty = threadIdx.x >> 5;
  #pragma unroll
  for (int i = 0; i < 4; ++i) {
    const int s = s0 + ty + i * 8;
    t[ty + i * 8][tx] = lin(x, ((size_t)(b * SS) + s) * CC + c0 + tx, f32);
  }
  __syncthreads();
  #pragma unroll
  for (int i = 0; i < 4; ++i) {
    const int c = c0 + ty + i * 8;
    const float mu = meanb[b * CC + c], sd = stdb[b * CC + c];
    xTc[((size_t)(lb * CC) + c) * SS + s0 + tx] = (t[tx][ty + i * 8] - mu) / sd;
  }
}

// ---------------- weight convert+transpose: W (KxN, input dtype) -> bf16 (NxK)
__global__ __launch_bounds__(256) void transpose_w(
    const void* __restrict__ W, ushort* __restrict__ Wt, int K, int N,
    const int* __restrict__ dtf)
{
  const int f32 = *dtf;
  __shared__ float t[32][33];
  const int n0 = blockIdx.x * 32, k0 = blockIdx.y * 32;
  const int tx = threadIdx.x & 31, ty = threadIdx.x >> 5;
  #pragma unroll
  for (int i = 0; i < 4; ++i)
    t[ty + i * 8][tx] = lin(W, (size_t)(k0 + ty + i * 8) * N + n0 + tx, f32);
  __syncthreads();
  #pragma unroll
  for (int i = 0; i < 4; ++i)
    Wt[(size_t)(n0 + ty + i * 8) * K + k0 + tx] = f2b(t[tx][ty + i * 8]);
}

// ---------------- generic fp32 tiled GEMM (stage-1 + fallback) ----------
enum GemmMode { M_BIAS = 0, M_BIAS_RELU = 1, M_RELU_PE = 2,
                M_ADD_BIAS_LEAKY = 3, M_ADD_BIAS_ELU = 4, M_ADD_BIAS = 5 };

template<typename AT, typename ADT, typename OT, int MODE>
__global__ __launch_bounds__(256) void gemm_kernel(
    const AT* __restrict__ A, const void* __restrict__ Bw,
    const void* __restrict__ bias, const ADT* __restrict__ addend,
    OT* __restrict__ Cout, int M, int K, int Nn, const int* __restrict__ dtf)
{
  const int f32 = *dtf;
  __shared__ __align__(16) float As[16][68];
  __shared__ __align__(16) float Bs[16][68];
  const int tid = threadIdx.x;
  const int m0 = blockIdx.y * 64, n0 = blockIdx.x * 64;
  const int tx = tid & 15, ty = tid >> 4;
  const int la_m = tid >> 2, la_k = (tid & 3) * 4;
  const int lb_k = tid >> 4, lb_n = (tid & 15) * 4;
  float acc[4][4];
  #pragma unroll
  for (int i = 0; i < 4; ++i)
    #pragma unroll
    for (int j = 0; j < 4; ++j) acc[i][j] = 0.f;
  const size_t a_row = (size_t)(m0 + la_m) * K;

  for (int k0 = 0; k0 < K; k0 += 16) {
    if constexpr (sizeof(AT) == 4) {
      const float4 av = *reinterpret_cast<const float4*>(A + a_row + k0 + la_k);
      As[la_k + 0][la_m] = av.x; As[la_k + 1][la_m] = av.y;
      As[la_k + 2][la_m] = av.z; As[la_k + 3][la_m] = av.w;
    } else {
      const ushort4 av = *reinterpret_cast<const ushort4*>(A + a_row + k0 + la_k);
      As[la_k + 0][la_m] = b2f(av.x); As[la_k + 1][la_m] = b2f(av.y);
      As[la_k + 2][la_m] = b2f(av.z); As[la_k + 3][la_m] = b2f(av.w);
    }
    {
      const size_t boff = (size_t)(k0 + lb_k) * Nn + n0 + lb_n;
      if (f32) {
        const float4 bv = *reinterpret_cast<const float4*>((const float*)Bw + boff);
        Bs[lb_k][lb_n + 0] = bv.x; Bs[lb_k][lb_n + 1] = bv.y;
        Bs[lb_k][lb_n + 2] = bv.z; Bs[lb_k][lb_n + 3] = bv.w;
      } else {
        const ushort4 bv = *reinterpret_cast<const ushort4*>((const ushort*)Bw + boff);
        Bs[lb_k][lb_n + 0] = b2f(bv.x); Bs[lb_k][lb_n + 1] = b2f(bv.y);
        Bs[lb_k][lb_n + 2] = b2f(bv.z); Bs[lb_k][lb_n + 3] = b2f(bv.w);
      }
    }
    __syncthreads();
    #pragma unroll
    for (int k = 0; k < 16; ++k) {
      const float4 a4 = *reinterpret_cast<const float4*>(&As[k][ty * 4]);
      const float4 b4 = *reinterpret_cast<const float4*>(&Bs[k][tx * 4]);
      const float aa[4] = {a4.x, a4.y, a4.z, a4.w};
      const float bb[4] = {b4.x, b4.y, b4.z, b4.w};
      #pragma unroll
      for (int i = 0; i < 4; ++i)
        #pragma unroll
        for (int j = 0; j < 4; ++j)
          acc[i][j] = fmaf(aa[i], bb[j], acc[i][j]);
    }
    __syncthreads();
  }

  float biasv[4];
  if constexpr (MODE != M_RELU_PE) {
    #pragma unroll
    for (int j = 0; j < 4; ++j) biasv[j] = lin(bias, n0 + tx * 4 + j, f32);
  }
  #pragma unroll
  for (int i = 0; i < 4; ++i) {
    const int m = m0 + ty * 4 + i;
    #pragma unroll
    for (int j = 0; j < 4; ++j) {
      const int n = n0 + tx * 4 + j;
      float v = acc[i][j];
      if constexpr (MODE == M_BIAS) {
        v += biasv[j];
      } else if constexpr (MODE == M_BIAS_RELU) {
        v = fmaxf(v + biasv[j], 0.f);
      } else if constexpr (MODE == M_RELU_PE) {
        v = fmaxf(v, 0.f);
        const float freq = expf((float)(n & ~1) * (-0.017988946f)); // -ln(1e4)/512
        const float ang  = (float)(m & (CC - 1)) * freq;            // pos = c
        v += (n & 1) ? cosf(ang) : sinf(ang);
      } else {
        float ad;
        if constexpr (sizeof(ADT) == 4) ad = ((const float*)addend)[(size_t)m * Nn + n];
        else                            ad = b2f(((const ushort*)addend)[(size_t)m * Nn + n]);
        v = ad + v + biasv[j];
        if constexpr (MODE == M_ADD_BIAS_LEAKY) v = (v >= 0.f) ? v : 0.5f * v;
        else if constexpr (MODE == M_ADD_BIAS_ELU) v = (v > 0.f) ? v : expm1f(v);
      }
      if constexpr (sizeof(OT) == 4) ((float*)Cout)[(size_t)m * Nn + n] = v;
      else                           ((ushort*)Cout)[(size_t)m * Nn + n] = f2b(v);
    }
  }
}

template<typename AT, typename ADT, typename OT, int MODE>
static void launch_gemm(const void* A, const void* Bw, const void* bias, const void* add,
                        void* Cout, int M, int K, int Nn, const int* dtf, hipStream_t stream)
{
  dim3 grid(Nn / 64, M / 64);
  gemm_kernel<AT, ADT, OT, MODE><<<grid, dim3(256), 0, stream>>>(
      (const AT*)A, Bw, bias, (const ADT*)add, (OT*)Cout, M, K, Nn, dtf);
}

// ---------------- MFMA bf16 GEMM: Cout = epi(A @ Wt^T) ----------------
template<typename ADT, typename OT, int MODE>
__global__ __launch_bounds__(256) void mgemm_kernel(
    const ushort* __restrict__ A, const ushort* __restrict__ Wt,
    const void* __restrict__ bias, const ADT* __restrict__ addend,
    OT* __restrict__ Cout, int M, int K, int Nn, const int* __restrict__ dtf)
{
  const int f32 = *dtf;
  __shared__ __align__(16) ushort As[128][40];
  __shared__ __align__(16) ushort Bs[128][40];
  const int tid = threadIdx.x;
  const int m0 = blockIdx.y * 128, n0 = blockIdx.x * 128;
  const int wave = tid >> 6, lane = tid & 63;
  const int wm = wave & 1, wn = wave >> 1;
  const int quad = lane >> 4, l15 = lane & 15;

  f32x4 acc[4][4];
  #pragma unroll
  for (int i = 0; i < 4; ++i)
    #pragma unroll
    for (int j = 0; j < 4; ++j) acc[i][j] = (f32x4){0.f, 0.f, 0.f, 0.f};

  const int srow = tid >> 1, sseg = (tid & 1) * 16;
  const size_t a_base = (size_t)(m0 + srow) * K + sseg;
  const size_t b_base = (size_t)(n0 + srow) * K + sseg;

  for (int k0 = 0; k0 < K; k0 += 32) {
    {
      const float4* ga = reinterpret_cast<const float4*>(A + a_base + k0);
      const float4* gb = reinterpret_cast<const float4*>(Wt + b_base + k0);
      const float4 a0 = ga[0], a1 = ga[1];
      const float4 b0 = gb[0], b1 = gb[1];
      float4* da = reinterpret_cast<float4*>(&As[srow][sseg]);
      float4* db = reinterpret_cast<float4*>(&Bs[srow][sseg]);
      da[0] = a0; da[1] = a1;
      db[0] = b0; db[1] = b1;
    }
    __syncthreads();
    short8 af[4], bf[4];
    #pragma unroll
    for (int i = 0; i < 4; ++i)
      af[i] = *reinterpret_cast<const short8*>(&As[wm * 64 + i * 16 + l15][quad * 8]);
    #pragma unroll
    for (int j = 0; j < 4; ++j)
      bf[j] = *reinterpret_cast<const short8*>(&Bs[wn * 64 + j * 16 + l15][quad * 8]);
    #pragma unroll
    for (int i = 0; i < 4; ++i)
      #pragma unroll
      for (int j = 0; j < 4; ++j)
        acc[i][j] = __builtin_amdgcn_mfma_f32_16x16x32_bf16(af[i], bf[j], acc[i][j], 0, 0, 0);
    __syncthreads();
  }

  #pragma unroll
  for (int j = 0; j < 4; ++j) {
    const int n = n0 + wn * 64 + j * 16 + l15;
    const float bv = lin(bias, n, f32);
    #pragma unroll
    for (int i = 0; i < 4; ++i) {
      #pragma unroll
      for (int r = 0; r < 4; ++r) {
        const int m = m0 + wm * 64 + i * 16 + quad * 4 + r;
        float v = acc[i][j][r];
        if constexpr (MODE == M_BIAS) {
          v += bv;
        } else if constexpr (MODE == M_BIAS_RELU) {
          v = fmaxf(v + bv, 0.f);
        } else {
          float ad;
          if constexpr (sizeof(ADT) == 4) ad = ((const float*)addend)[(size_t)m * Nn + n];
          else                            ad = b2f(((const ushort*)addend)[(size_t)m * Nn + n]);
          v = ad + v + bv;
          if constexpr (MODE == M_ADD_BIAS_ELU)   v = (v > 0.f) ? v : expm1f(v);
          else if constexpr (MODE == M_ADD_BIAS_LEAKY) v = (v >= 0.f) ? v : 0.5f * v;
        }
        if constexpr (sizeof(OT) == 4) ((float*)Cout)[(size_t)m * Nn + n] = v;
        else                           ((ushort*)Cout)[(size_t)m * Nn + n] = f2b(v);
      }
    }
  }
}

template<typename ADT, typename OT, int MODE>
static void launch_mgemm(const void* A, const void* Wt, const void* bias, const void* add,
                         void* Cout, int M, int K, int Nn, const int* dtf, hipStream_t stream)
{
  dim3 grid(Nn / 128, M / 128);
  mgemm_kernel<ADT, OT, MODE><<<grid, dim3(256), 0, stream>>>(
      (const ushort*)A, (const ushort*)Wt, bias, (const ADT*)add, (OT*)Cout, M, K, Nn, dtf);
}

// ---------------- GAttn: wave-per-row top-k masked softmax attention -------
// grid (CC/4, HH, BPC), block 256 = 4 waves; wave w handles row l0+w.
// q row in 16 float4 regs; kt stride 68 (16B-aligned b128, 2-way = free);
// ww read as float4. c8 loop NOT unrolled (VGPR budget ~90).
template<typename OT>
__global__ __launch_bounds__(256) void gattn_kernel(
    const float* __restrict__ q, const float* __restrict__ k,
    const float* __restrict__ v, OT* __restrict__ out)
{
  const int tid = threadIdx.x;
  const int wave = tid >> 6, lane = tid & 63;
  const int l0 = blockIdx.x * 4;
  const int h = blockIdx.y, bz = blockIdx.z;
  const int l = l0 + wave;
  const size_t base = ((size_t)bz * CC) * DD + h * EE;

  __shared__ __align__(16) float kt[64][68];
  __shared__ __align__(16) float ww[4][512];

  // q row -> registers (wave-uniform broadcast loads)
  float4 qv[16];
  {
    const float4* qp = reinterpret_cast<const float4*>(q + ((size_t)bz * CC + l) * DD + h * EE);
    #pragma unroll
    for (int i = 0; i < 16; ++i) qv[i] = qp[i];
  }

  float sc[8];
  const int sl = tid >> 4;            // 0..15
  const int e4 = (tid & 15) * 4;      // 0..60
  for (int c8 = 0; c8 < 8; ++c8) {    // NOT unrolled
    #pragma unroll
    for (int r = 0; r < 4; ++r) {
      const int s_local = sl + r * 16;
      const float4 kv = *reinterpret_cast<const float4*>(
          k + base + (size_t)(c8 * 64 + s_local) * DD + e4);
      *reinterpret_cast<float4*>(&kt[s_local][e4]) = kv;
    }
    __syncthreads();
    float a = 0.f;
    #pragma unroll
    for (int e = 0; e < 16; ++e) {
      const float4 kv = *reinterpret_cast<const float4*>(&kt[lane][e * 4]);
      a += qv[e].x * kv.x + qv[e].y * kv.y + qv[e].z * kv.z + qv[e].w * kv.w;
    }
    sc[c8] = a;
    __syncthreads();
  }

  // top-10 via wave shuffles
  float wk[8];
  #pragma unroll
  for (int j = 0; j < 8; ++j) wk[j] = sc[j];
  float maxv = 0.f, thr = 0.f;
  for (int it = 0; it < 10; ++it) {
    float lm = wk[0];
    #pragma unroll
    for (int j = 1; j < 8; ++j) lm = fmaxf(lm, wk[j]);
    float gm = lm;
    #pragma unroll
    for (int off = 32; off > 0; off >>= 1) gm = fmaxf(gm, __shfl_xor(gm, off));
    if (it == 0) maxv = gm;
    if (it == 9) { thr = gm; break; }
    const unsigned long long msk = __ballot(lm == gm);
    if (lane == __ffsll(msk) - 1) {
      #pragma unroll
      for (int j = 0; j < 8; ++j) { if (wk[j] == gm) { wk[j] = -FLT_MAX; break; } }
    }
  }

  float lsum = 0.f;
  #pragma unroll
  for (int j = 0; j < 8; ++j) {
    const float p = (sc[j] >= thr) ? expf((sc[j] - maxv) * 0.125f) : 0.f;
    ww[wave][j * 64 + lane] = p;
    lsum += p;
  }
  #pragma unroll
  for (int off = 32; off > 0; off >>= 1) lsum += __shfl_xor(lsum, off);
  const float inv = 1.f / lsum;
  __syncthreads();

  // A @ v: lane owns e = lane; ww read as float4 broadcasts
  float acc = 0.f;
  const float* vp = v + base + lane;
  const float* wp = ww[wave];
  for (int s = 0; s < 512; s += 4) {
    const float4 w4 = *reinterpret_cast<const float4*>(&wp[s]);
    acc = fmaf(w4.x, vp[(size_t)(s + 0) * DD], acc);
    acc = fmaf(w4.y, vp[(size_t)(s + 1) * DD], acc);
    acc = fmaf(w4.z, vp[(size_t)(s + 2) * DD], acc);
    acc = fmaf(w4.w, vp[(size_t)(s + 3) * DD], acc);
  }
  const float res = acc * inv;
  const size_t oi = ((size_t)bz * CC + l) * DD + h * EE + lane;
  if constexpr (sizeof(OT) == 4) out[oi] = res;
  else                           out[oi] = f2b(res);
}

// ---------------- pwattn1 (seq=512, pred=2048) ----------------
__global__ __launch_bounds__(128) void pwattn1_kernel(
    const ushort* __restrict__ query, const float* __restrict__ k1,
    const float* __restrict__ v1, ushort* __restrict__ V1)
{
  const int n = blockIdx.x, tid = threadIdx.x;
  __shared__ float ks[512], vs[512];
  __shared__ float Am[128][33];
  for (int i = tid; i < 512; i += 128) { ks[i] = k1[(size_t)n * 512 + i]; vs[i] = v1[(size_t)n * 512 + i]; }
  __syncthreads();
  {
    const int l = tid;
    float qv[16];
    const ushort* qp = query + (size_t)n * DFF + l * 16;
    #pragma unroll
    for (int e = 0; e < 16; ++e) qv[e] = b2f(qp[e]);
    float scl[32], mx = -FLT_MAX;
    #pragma unroll
    for (int s = 0; s < 32; ++s) {
      float a = 0.f;
      #pragma unroll
      for (int e = 0; e < 16; ++e) a += qv[e] * ks[s * 16 + e];
      scl[s] = a; mx = fmaxf(mx, a);
    }
    float sum = 0.f;
    #pragma unroll
    for (int s = 0; s < 32; ++s) { const float p = expf((scl[s] - mx) * 0.25f); scl[s] = p; sum += p; }
    const float invs = 1.f / sum;
    #pragma unroll
    for (int s = 0; s < 32; ++s) Am[l][s] = scl[s] * invs;
  }
  __syncthreads();
  #pragma unroll
  for (int r = 0; r < 16; ++r) {
    const int idx = tid + 128 * r;
    const int l = idx >> 4, e = idx & 15;
    float a = 0.f;
    #pragma unroll
    for (int s = 0; s < 32; ++s) a += Am[l][s] * vs[s * 16 + e];
    V1[(size_t)n * DFF + idx] = f2b(a);
  }
}

// ---------------- LayerNorm over 2048, in-place bf16 ----------------
__global__ __launch_bounds__(256) void ln_kernel(
    ushort* __restrict__ h, const void* __restrict__ g, const void* __restrict__ bt,
    const int* __restrict__ dtf)
{
  const int f32 = *dtf;
  const int n = blockIdx.x, tid = threadIdx.x;
  ushort* hp = h + (size_t)n * DFF;
  float x[8]; float s = 0.f, s2 = 0.f;
  #pragma unroll
  for (int i = 0; i < 8; ++i) {
    const float xv = b2f(hp[tid + 256 * i]);
    x[i] = xv; s += xv; s2 += xv * xv;
  }
  __shared__ float rs[256], rq[256];
  rs[tid] = s; rq[tid] = s2;
  __syncthreads();
  for (int off = 128; off > 0; off >>= 1) {
    if (tid < off) { rs[tid] += rs[tid + off]; rq[tid] += rq[tid + off]; }
    __syncthreads();
  }
  const float mu  = rs[0] * (1.f / DFF);
  const float var = rq[0] * (1.f / DFF) - mu * mu;
  const float inv = rsqrtf(var + 1e-5f);
  #pragma unroll
  for (int i = 0; i < 8; ++i) {
    const int d = tid + 256 * i;
    hp[d] = f2b((x[i] - mu) * inv * lin(g, d, f32) + lin(bt, d, f32));
  }
}

// ---------------- pwattn2 (seq=2048, pred=512), templated output -----------
template<typename OT>
__global__ __launch_bounds__(128) void pwattn2_kernel(
    const float* __restrict__ query2, const ushort* __restrict__ k2,
    const ushort* __restrict__ v2, OT* __restrict__ V2)
{
  const int n = blockIdx.x, tid = threadIdx.x;
  __shared__ float ks[2048], vs[2048];
  __shared__ float Am[32][129];
  for (int i = tid; i < 2048; i += 128) {
    ks[i] = b2f(k2[(size_t)n * DFF + i]);
    vs[i] = b2f(v2[(size_t)n * DFF + i]);
  }
  __syncthreads();
  if (tid < 32) {
    const int l = tid;
    float qv[16];
    #pragma unroll
    for (int e = 0; e < 16; ++e) qv[e] = query2[(size_t)n * 512 + l * 16 + e];
    float mx = -FLT_MAX;
    for (int s = 0; s < 128; ++s) {
      float a = 0.f;
      #pragma unroll
      for (int e = 0; e < 16; ++e) a += qv[e] * ks[s * 16 + e];
      Am[l][s] = a; mx = fmaxf(mx, a);
    }
    float sum = 0.f;
    for (int s = 0; s < 128; ++s) { const float p = expf((Am[l][s] - mx) * 0.25f); Am[l][s] = p; sum += p; }
    const float invs = 1.f / sum;
    for (int s = 0; s < 128; ++s) Am[l][s] *= invs;
  }
  __syncthreads();
  #pragma unroll
  for (int r = 0; r < 4; ++r) {
    const int idx = tid + 128 * r;
    const int l = idx >> 4, e = idx & 15;
    float a = 0.f;
    for (int s = 0; s < 128; ++s) a += Am[l][s] * vs[s * 16 + e];
    if constexpr (sizeof(OT) == 4) V2[(size_t)n * 512 + idx] = a;
    else                           V2[(size_t)n * 512 + idx] = f2b(a);
  }
}

// ---------------- final: dec = y@fc_w + fc_b; out = dec*std+mean -----------
__global__ __launch_bounds__(128) void final_kernel(
    const float* __restrict__ y, const void* __restrict__ fc_w,
    const void* __restrict__ fc_b, const float* __restrict__ meanb,
    const float* __restrict__ stdb, void* __restrict__ out, int row_base,
    const int* __restrict__ dtf)
{
  const int f32 = *dtf;
  const int row = row_base + blockIdx.x;
  const int b = row >> 9, c = row & 511;
  const int tid = threadIdx.x;
  __shared__ float yr[512];
  for (int i = tid; i < 512; i += 128) yr[i] = y[(size_t)blockIdx.x * 512 + i];
  __syncthreads();
  if (tid < PRED) {
    float a = 0.f;
    for (int d = 0; d < 512; ++d) a += yr[d] * lin(fc_w, d * PRED + tid, f32);
    a += lin(fc_b, tid, f32);
    const float r = a * stdb[row] + meanb[row];
    const size_t oi = ((size_t)b * PRED + tid) * CC + c;
    if (f32) ((float*)out)[oi] = r;
    else     ((ushort*)out)[oi] = f2b(r);
  }
}

// ---------------------------------------------------------------------------
extern "C" void kernel_launch(void* const* d_in, const int* in_sizes, int n_in,
                              void* d_out, int out_size, void* d_ws, size_t ws_size,
                              hipStream_t stream)
{
  (void)in_sizes; (void)n_in; (void)out_size;
  const void* x_enc   = d_in[0];
  const void* embed_w = d_in[4];
  const void* q_w = d_in[5],  * q_b = d_in[6];
  const void* k_w = d_in[7],  * k_b = d_in[8];
  const void* v_w = d_in[9],  * v_b = d_in[10];
  const void* o_w = d_in[11], * o_b = d_in[12];
  const void* enc_w = d_in[13], * enc_b = d_in[14];
  const void* f1q_w = d_in[15], * f1q_b = d_in[16];
  const void* f1k_w = d_in[17], * f1k_b = d_in[18];
  const void* f1v_w = d_in[19], * f1v_b = d_in[20];
  const void* f1o_w = d_in[21], * f1o_b = d_in[22];
  const void* f2q_w = d_in[23], * f2q_b = d_in[24];
  const void* f2k_w = d_in[25], * f2k_b = d_in[26];
  const void* f2v_w = d_in[27], * f2v_b = d_in[28];
  const void* f2o_w = d_in[29], * f2o_b = d_in[30];
  const void* ln_g  = d_in[31], * ln_b  = d_in[32];
  const void* fc_w  = d_in[33], * fc_b  = d_in[34];

  const size_t HDR = 131072 + 1024;
  const size_t E_F1Q = 512ull * 2048, E_F1O = 2048ull * 2048, E_F2Q = 2048ull * 512;
  const size_t E_F2K = 2048ull * 2048, E_F2V = 2048ull * 2048, E_F2O = 512ull * 512;
  const size_t E_SQ  = 512ull * 512;   // o_w, enc_w, f1k_w, f1v_w each
  const size_t WT_EL = E_F1Q + E_F1O + E_F2Q + E_F2K + E_F2V + E_F2O + 4 * E_SQ;
  const size_t WT_BYTES = WT_EL * 2;   // ~30.5 MB
  const size_t PER_BATCH = 5ull * 512 * 512 * 4 + 3ull * 512 * DFF * 2; // 11.53MB

  const int use_mfma = (HDR + WT_BYTES + PER_BATCH <= ws_size) ? 1 : 0;
  const size_t FIXED = HDR + (use_mfma ? WT_BYTES : 0);
  int BPC = 1;
  for (int c = 8; c >= 1; c >>= 1) {
    if (FIXED + (size_t)c * PER_BATCH <= ws_size) { BPC = c; break; }
  }
  const int R = BPC * 512;

  char* ws = (char*)d_ws;
  float* meanb = (float*)ws;
  float* stdb  = (float*)(ws + 65536);
  int*   dtf   = (int*)(ws + 131072);
  ushort* wt_base = (ushort*)(ws + HDR);
  ushort* wt_f1q = wt_base;
  ushort* wt_f1o = wt_f1q + E_F1Q;
  ushort* wt_f2q = wt_f1o + E_F1O;
  ushort* wt_f2k = wt_f2q + E_F2Q;
  ushort* wt_f2v = wt_f2k + E_F2K;
  ushort* wt_f2o = wt_f2v + E_F2V;
  ushort* wt_o   = wt_f2o + E_F2O;
  ushort* wt_enc = wt_o   + E_SQ;
  ushort* wt_f1k = wt_enc + E_SQ;
  ushort* wt_f1v = wt_f1k + E_SQ;
  char* arena = ws + FIXED;
  const size_t FSL = (size_t)R * 512 * 4;
  const size_t GSL = (size_t)R * DFF * 2;
  void* A_ = arena;
  void* B_ = arena + FSL;
  void* C_ = arena + 2 * FSL;
  void* D_ = arena + 3 * FSL;
  void* E_ = arena + 4 * FSL;
  void* G1 = arena + 5 * FSL;
  void* G2 = arena + 5 * FSL + GSL;
  void* G3 = arena + 5 * FSL + 2 * GSL;

  detect_dtype<<<1, 256, 0, stream>>>((const ushort*)x_enc, dtf);
  instnorm_stats<<<dim3(2, NB), 256, 0, stream>>>(x_enc, meanb, stdb, dtf);

  if (use_mfma) {   // one-time weight convert+transpose (KxN -> bf16 NxK)
    transpose_w<<<dim3(DFF / 32, 512 / 32), 256, 0, stream>>>(f1q_w, wt_f1q, 512, DFF, dtf);
    transpose_w<<<dim3(DFF / 32, DFF / 32), 256, 0, stream>>>(f1o_w, wt_f1o, DFF, DFF, dtf);
    transpose_w<<<dim3(512 / 32, DFF / 32), 256, 0, stream>>>(f2q_w, wt_f2q, DFF, 512, dtf);
    transpose_w<<<dim3(DFF / 32, DFF / 32), 256, 0, stream>>>(f2k_w, wt_f2k, DFF, DFF, dtf);
    transpose_w<<<dim3(DFF / 32, DFF / 32), 256, 0, stream>>>(f2v_w, wt_f2v, DFF, DFF, dtf);
    transpose_w<<<dim3(512 / 32, 512 / 32), 256, 0, stream>>>(f2o_w, wt_f2o, 512, 512, dtf);
    transpose_w<<<dim3(512 / 32, 512 / 32), 256, 0, stream>>>(o_w,   wt_o,   512, 512, dtf);
    transpose_w<<<dim3(512 / 32, 512 / 32), 256, 0, stream>>>(enc_w, wt_enc, 512, 512, dtf);
    transpose_w<<<dim3(512 / 32, 512 / 32), 256, 0, stream>>>(f1k_w, wt_f1k, 512, 512, dtf);
    transpose_w<<<dim3(512 / 32, 512 / 32), 256, 0, stream>>>(f1v_w, wt_f1v, 512, 512, dtf);
  }

  for (int bc = 0; bc < NB / BPC; ++bc) {
    const int b0 = bc * BPC;
    // --- stage 1 (fp32: feeds top-k mask) ---
    norm_transpose<<<dim3(16, 16, BPC), 256, 0, stream>>>(x_enc, meanb, stdb, (float*)A_, b0, dtf);
    launch_gemm<float, float, float, M_RELU_PE >(A_, embed_w, nullptr, nullptr, B_, R, 512, 512, dtf, stream); // emb
    launch_gemm<float, float, float, M_BIAS_RELU>(B_, q_w, q_b, nullptr, C_, R, 512, 512, dtf, stream);        // q
    launch_gemm<float, float, float, M_BIAS     >(B_, k_w, k_b, nullptr, D_, R, 512, 512, dtf, stream);        // k
    launch_gemm<float, float, float, M_BIAS_RELU>(B_, v_w, v_b, nullptr, E_, R, 512, 512, dtf, stream);        // v

    if (use_mfma) {
      gattn_kernel<ushort><<<dim3(CC / 4, HH, BPC), 256, 0, stream>>>(
          (float*)C_, (float*)D_, (float*)E_, (ushort*)A_);                                          // attn bf16
      launch_mgemm<float, ushort, M_ADD_BIAS_LEAKY>(A_, wt_o, o_b, B_, C_, R, 512, 512, dtf, stream); // y bf16
      launch_mgemm<float, ushort, M_BIAS>(C_, wt_enc, enc_b, nullptr, D_, R, 512, 512, dtf, stream);  // X1 bf16
      // --- stage 2: pwattn1 + LN ---
      launch_mgemm<float, ushort, M_BIAS_RELU>(D_, wt_f1q, f1q_b, nullptr, G1, R, 512, DFF, dtf, stream); // query1
      launch_mgemm<float, float,  M_BIAS     >(D_, wt_f1k, f1k_b, nullptr, A_, R, 512, 512, dtf, stream); // k1 f32
      launch_mgemm<float, float,  M_BIAS_RELU>(D_, wt_f1v, f1v_b, nullptr, B_, R, 512, 512, dtf, stream); // v1 f32
      pwattn1_kernel<<<R, 128, 0, stream>>>((const ushort*)G1, (const float*)A_, (const float*)B_, (ushort*)G2);
      launch_mgemm<ushort, ushort, M_ADD_BIAS_ELU>(G2, wt_f1o, f1o_b, G1, G1, R, DFF, DFF, dtf, stream);  // h
      ln_kernel<<<R, 256, 0, stream>>>((ushort*)G1, ln_g, ln_b, dtf);
      // --- stage 3: pwattn2 + out ---
      launch_mgemm<float, float,  M_BIAS_RELU>(G1, wt_f2q, f2q_b, nullptr, A_, R, DFF, 512, dtf, stream); // query2
      launch_mgemm<float, ushort, M_BIAS     >(G1, wt_f2k, f2k_b, nullptr, G2, R, DFF, DFF, dtf, stream); // k2
      launch_mgemm<float, ushort, M_BIAS_RELU>(G1, wt_f2v, f2v_b, nullptr, G3, R, DFF, DFF, dtf, stream); // v2
      pwattn2_kernel<ushort><<<R, 128, 0, stream>>>((const float*)A_, (const ushort*)G2, (const ushort*)G3, (ushort*)B_);
      launch_mgemm<float, float, M_ADD_BIAS>(B_, wt_f2o, f2o_b, A_, C_, R, 512, 512, dtf, stream);        // y2
    } else {
      gattn_kernel<float><<<dim3(CC / 4, HH, BPC), 256, 0, stream>>>(
          (float*)C_, (float*)D_, (float*)E_, (float*)A_);
      launch_gemm<float, float, float, M_ADD_BIAS_LEAKY>(A_, o_w, o_b, B_, C_, R, 512, 512, dtf, stream);
      launch_gemm<float, float, float, M_BIAS>(C_, enc_w, enc_b, nullptr, D_, R, 512, 512, dtf, stream);
      launch_gemm<float, float, ushort, M_BIAS_RELU>(D_, f1q_w, f1q_b, nullptr, G1, R, 512, DFF, dtf, stream);
      launch_gemm<float, float, float,  M_BIAS     >(D_, f1k_w, f1k_b, nullptr, A_, R, 512, 512, dtf, stream);
      launch_gemm<float, float, float,  M_BIAS_RELU>(D_, f1v_w, f1v_b, nullptr, B_, R, 512, 512, dtf, stream);
      pwattn1_kernel<<<R, 128, 0, stream>>>((const ushort*)G1, (const float*)A_, (const float*)B_, (ushort*)G2);
      launch_gemm<ushort, ushort, ushort, M_ADD_BIAS_ELU>(G2, f1o_w, f1o_b, G1, G1, R, DFF, DFF, dtf, stream);
      ln_kernel<<<R, 256, 0, stream>>>((ushort*)G1, ln_g, ln_b, dtf);
      launch_gemm<ushort, float, float,  M_BIAS_RELU>(G1, f2q_w, f2q_b, nullptr, A_, R, DFF, 512, dtf, stream);
      launch_gemm<ushort, float, ushort, M_BIAS     >(G1, f2k_w, f2k_b, nullptr, G2, R, DFF, DFF, dtf, stream);
      launch_gemm<ushort, float, ushort, M_BIAS_RELU>(G1, f2v_w, f2v_b, nullptr, G3, R, DFF, DFF, dtf, stream);
      pwattn2_kernel<float><<<R, 128, 0, stream>>>((const float*)A_, (const ushort*)G2, (const ushort*)G3, (float*)B_);
      launch_gemm<float, float, float, M_ADD_BIAS>(B_, f2o_w, f2o_b, A_, C_, R, 512, 512, dtf, stream);
    }
    final_kernel<<<R, 128, 0, stream>>>((const float*)C_, fc_w, fc_b, meanb, stdb, d_out, b0 * 512, dtf);
  }
}

// Round 10
// 4231.562 us; speedup vs baseline: 1.3038x; 1.3038x over previous
//
#include <hip/hip_runtime.h>
#include <float.h>
#include <math.h>
#include <stdint.h>

// ---------------------------------------------------------------------------
// Model_33062658245168: Informer-style time-series model. fp32 in/out
// (runtime-detected; bf16 fallback kept). B=32 S=512 C=512 D=512 DF=2048 H=8
// E=64 P=16 PRED=96 K(topk)=10, N=16384.
//
// Round 10: gattn = round-9 b128 LDS patterns (kt stride 68, ww float4;
// measured conflict-free) + round-8 register footprint (q row in LDS, read
// as wave-uniform float4 broadcasts, NOT hoisted to 64 VGPRs -> round-9's
// occupancy collapse 55%->23% was the regression cause).
// ---------------------------------------------------------------------------

#define NB   32
#define SS   512
#define CC   512
#define DD   512
#define DFF  2048
#define HH   8
#define EE   64
#define PRED 96

typedef __attribute__((ext_vector_type(8))) short short8;
typedef __attribute__((ext_vector_type(4))) float f32x4;

__device__ __forceinline__ float b2f(ushort u) {
  union { float f; uint32_t i; } c; c.i = ((uint32_t)u) << 16; return c.f;
}
__device__ __forceinline__ ushort f2b(float f) {
  union { float f; uint32_t i; } c; c.f = f;
  uint32_t x = c.i;
  return (ushort)((x + 0x7fffu + ((x >> 16) & 1u)) >> 16);   // RNE
}
__device__ __forceinline__ float lin(const void* p, size_t i, int f32) {
  return f32 ? ((const float*)p)[i] : b2f(((const ushort*)p)[i]);
}

// ---------------- dtype detection (1 = fp32 inputs) ----------------
__global__ __launch_bounds__(256) void detect_dtype(
    const ushort* __restrict__ x, int* __restrict__ flag)
{
  __shared__ float red[256];
  const int t = threadIdx.x;
  float v = fabsf(b2f(x[2 * t]));
  if (!(v < 1e30f)) v = 1e30f;
  red[t] = v;
  __syncthreads();
  for (int off = 128; off > 0; off >>= 1) {
    if (t < off) red[t] = fmaxf(red[t], red[t + off]);
    __syncthreads();
  }
  if (t == 0) flag[0] = (red[0] > 1e6f) ? 1 : 0;
}

// ---------------- instance norm stats ----------------
__global__ __launch_bounds__(256) void instnorm_stats(
    const void* __restrict__ x, float* __restrict__ meanb, float* __restrict__ stdb,
    const int* __restrict__ dtf)
{
  const int f32 = *dtf;
  const int c = blockIdx.x * 256 + threadIdx.x;
  const int b = blockIdx.y;
  float s = 0.f, s2 = 0.f;
  for (int t = 0; t < SS; ++t) {
    const float xv = lin(x, ((size_t)(b * SS) + t) * CC + c, f32);
    s += xv; s2 += xv * xv;
  }
  const float mu  = s * (1.f / SS);
  const float var = s2 * (1.f / SS) - mu * mu;
  meanb[b * CC + c] = mu;
  stdb [b * CC + c] = sqrtf(var + 1e-5f);
}

// ---------------- normalize + transpose one chunk ----------------
__global__ __launch_bounds__(256) void norm_transpose(
    const void* __restrict__ x, const float* __restrict__ meanb,
    const float* __restrict__ stdb, float* __restrict__ xTc, int b_base,
    const int* __restrict__ dtf)
{
  const int f32 = *dtf;
  __shared__ float t[32][33];
  const int s0 = blockIdx.x * 32, c0 = blockIdx.y * 32, lb = blockIdx.z;
  const int b = b_base + lb;
  const int tx = threadIdx.x & 31, ty = threadIdx.x >> 5;
  #pragma unroll
  for (int i = 0; i < 4; ++i) {
    const int s = s0 + ty + i * 8;
    t[ty + i * 8][tx] = lin(x, ((size_t)(b * SS) + s) * CC + c0 + tx, f32);
  }
  __syncthreads();
  #pragma unroll
  for (int i = 0; i < 4; ++i) {
    const int c = c0 + ty + i * 8;
    const float mu = meanb[b * CC + c], sd = stdb[b * CC + c];
    xTc[((size_t)(lb * CC) + c) * SS + s0 + tx] = (t[tx][ty + i * 8] - mu) / sd;
  }
}

// ---------------- weight convert+transpose: W (KxN, input dtype) -> bf16 (NxK)
__global__ __launch_bounds__(256) void transpose_w(
    const void* __restrict__ W, ushort* __restrict__ Wt, int K, int N,
    const int* __restrict__ dtf)
{
  const int f32 = *dtf;
  __shared__ float t[32][33];
  const int n0 = blockIdx.x * 32, k0 = blockIdx.y * 32;
  const int tx = threadIdx.x & 31, ty = threadIdx.x >> 5;
  #pragma unroll
  for (int i = 0; i < 4; ++i)
    t[ty + i * 8][tx] = lin(W, (size_t)(k0 + ty + i * 8) * N + n0 + tx, f32);
  __syncthreads();
  #pragma unroll
  for (int i = 0; i < 4; ++i)
    Wt[(size_t)(n0 + ty + i * 8) * K + k0 + tx] = f2b(t[tx][ty + i * 8]);
}

// ---------------- generic fp32 tiled GEMM (stage-1 + fallback) ----------
enum GemmMode { M_BIAS = 0, M_BIAS_RELU = 1, M_RELU_PE = 2,
                M_ADD_BIAS_LEAKY = 3, M_ADD_BIAS_ELU = 4, M_ADD_BIAS = 5 };

template<typename AT, typename ADT, typename OT, int MODE>
__global__ __launch_bounds__(256) void gemm_kernel(
    const AT* __restrict__ A, const void* __restrict__ Bw,
    const void* __restrict__ bias, const ADT* __restrict__ addend,
    OT* __restrict__ Cout, int M, int K, int Nn, const int* __restrict__ dtf)
{
  const int f32 = *dtf;
  __shared__ __align__(16) float As[16][68];
  __shared__ __align__(16) float Bs[16][68];
  const int tid = threadIdx.x;
  const int m0 = blockIdx.y * 64, n0 = blockIdx.x * 64;
  const int tx = tid & 15, ty = tid >> 4;
  const int la_m = tid >> 2, la_k = (tid & 3) * 4;
  const int lb_k = tid >> 4, lb_n = (tid & 15) * 4;
  float acc[4][4];
  #pragma unroll
  for (int i = 0; i < 4; ++i)
    #pragma unroll
    for (int j = 0; j < 4; ++j) acc[i][j] = 0.f;
  const size_t a_row = (size_t)(m0 + la_m) * K;

  for (int k0 = 0; k0 < K; k0 += 16) {
    if constexpr (sizeof(AT) == 4) {
      const float4 av = *reinterpret_cast<const float4*>(A + a_row + k0 + la_k);
      As[la_k + 0][la_m] = av.x; As[la_k + 1][la_m] = av.y;
      As[la_k + 2][la_m] = av.z; As[la_k + 3][la_m] = av.w;
    } else {
      const ushort4 av = *reinterpret_cast<const ushort4*>(A + a_row + k0 + la_k);
      As[la_k + 0][la_m] = b2f(av.x); As[la_k + 1][la_m] = b2f(av.y);
      As[la_k + 2][la_m] = b2f(av.z); As[la_k + 3][la_m] = b2f(av.w);
    }
    {
      const size_t boff = (size_t)(k0 + lb_k) * Nn + n0 + lb_n;
      if (f32) {
        const float4 bv = *reinterpret_cast<const float4*>((const float*)Bw + boff);
        Bs[lb_k][lb_n + 0] = bv.x; Bs[lb_k][lb_n + 1] = bv.y;
        Bs[lb_k][lb_n + 2] = bv.z; Bs[lb_k][lb_n + 3] = bv.w;
      } else {
        const ushort4 bv = *reinterpret_cast<const ushort4*>((const ushort*)Bw + boff);
        Bs[lb_k][lb_n + 0] = b2f(bv.x); Bs[lb_k][lb_n + 1] = b2f(bv.y);
        Bs[lb_k][lb_n + 2] = b2f(bv.z); Bs[lb_k][lb_n + 3] = b2f(bv.w);
      }
    }
    __syncthreads();
    #pragma unroll
    for (int k = 0; k < 16; ++k) {
      const float4 a4 = *reinterpret_cast<const float4*>(&As[k][ty * 4]);
      const float4 b4 = *reinterpret_cast<const float4*>(&Bs[k][tx * 4]);
      const float aa[4] = {a4.x, a4.y, a4.z, a4.w};
      const float bb[4] = {b4.x, b4.y, b4.z, b4.w};
      #pragma unroll
      for (int i = 0; i < 4; ++i)
        #pragma unroll
        for (int j = 0; j < 4; ++j)
          acc[i][j] = fmaf(aa[i], bb[j], acc[i][j]);
    }
    __syncthreads();
  }

  float biasv[4];
  if constexpr (MODE != M_RELU_PE) {
    #pragma unroll
    for (int j = 0; j < 4; ++j) biasv[j] = lin(bias, n0 + tx * 4 + j, f32);
  }
  #pragma unroll
  for (int i = 0; i < 4; ++i) {
    const int m = m0 + ty * 4 + i;
    #pragma unroll
    for (int j = 0; j < 4; ++j) {
      const int n = n0 + tx * 4 + j;
      float v = acc[i][j];
      if constexpr (MODE == M_BIAS) {
        v += biasv[j];
      } else if constexpr (MODE == M_BIAS_RELU) {
        v = fmaxf(v + biasv[j], 0.f);
      } else if constexpr (MODE == M_RELU_PE) {
        v = fmaxf(v, 0.f);
        const float freq = expf((float)(n & ~1) * (-0.017988946f)); // -ln(1e4)/512
        const float ang  = (float)(m & (CC - 1)) * freq;            // pos = c
        v += (n & 1) ? cosf(ang) : sinf(ang);
      } else {
        float ad;
        if constexpr (sizeof(ADT) == 4) ad = ((const float*)addend)[(size_t)m * Nn + n];
        else                            ad = b2f(((const ushort*)addend)[(size_t)m * Nn + n]);
        v = ad + v + biasv[j];
        if constexpr (MODE == M_ADD_BIAS_LEAKY) v = (v >= 0.f) ? v : 0.5f * v;
        else if constexpr (MODE == M_ADD_BIAS_ELU) v = (v > 0.f) ? v : expm1f(v);
      }
      if constexpr (sizeof(OT) == 4) ((float*)Cout)[(size_t)m * Nn + n] = v;
      else                           ((ushort*)Cout)[(size_t)m * Nn + n] = f2b(v);
    }
  }
}

template<typename AT, typename ADT, typename OT, int MODE>
static void launch_gemm(const void* A, const void* Bw, const void* bias, const void* add,
                        void* Cout, int M, int K, int Nn, const int* dtf, hipStream_t stream)
{
  dim3 grid(Nn / 64, M / 64);
  gemm_kernel<AT, ADT, OT, MODE><<<grid, dim3(256), 0, stream>>>(
      (const AT*)A, Bw, bias, (const ADT*)add, (OT*)Cout, M, K, Nn, dtf);
}

// ---------------- MFMA bf16 GEMM: Cout = epi(A @ Wt^T) ----------------
template<typename ADT, typename OT, int MODE>
__global__ __launch_bounds__(256) void mgemm_kernel(
    const ushort* __restrict__ A, const ushort* __restrict__ Wt,
    const void* __restrict__ bias, const ADT* __restrict__ addend,
    OT* __restrict__ Cout, int M, int K, int Nn, const int* __restrict__ dtf)
{
  const int f32 = *dtf;
  __shared__ __align__(16) ushort As[128][40];
  __shared__ __align__(16) ushort Bs[128][40];
  const int tid = threadIdx.x;
  const int m0 = blockIdx.y * 128, n0 = blockIdx.x * 128;
  const int wave = tid >> 6, lane = tid & 63;
  const int wm = wave & 1, wn = wave >> 1;
  const int quad = lane >> 4, l15 = lane & 15;

  f32x4 acc[4][4];
  #pragma unroll
  for (int i = 0; i < 4; ++i)
    #pragma unroll
    for (int j = 0; j < 4; ++j) acc[i][j] = (f32x4){0.f, 0.f, 0.f, 0.f};

  const int srow = tid >> 1, sseg = (tid & 1) * 16;
  const size_t a_base = (size_t)(m0 + srow) * K + sseg;
  const size_t b_base = (size_t)(n0 + srow) * K + sseg;

  for (int k0 = 0; k0 < K; k0 += 32) {
    {
      const float4* ga = reinterpret_cast<const float4*>(A + a_base + k0);
      const float4* gb = reinterpret_cast<const float4*>(Wt + b_base + k0);
      const float4 a0 = ga[0], a1 = ga[1];
      const float4 b0 = gb[0], b1 = gb[1];
      float4* da = reinterpret_cast<float4*>(&As[srow][sseg]);
      float4* db = reinterpret_cast<float4*>(&Bs[srow][sseg]);
      da[0] = a0; da[1] = a1;
      db[0] = b0; db[1] = b1;
    }
    __syncthreads();
    short8 af[4], bf[4];
    #pragma unroll
    for (int i = 0; i < 4; ++i)
      af[i] = *reinterpret_cast<const short8*>(&As[wm * 64 + i * 16 + l15][quad * 8]);
    #pragma unroll
    for (int j = 0; j < 4; ++j)
      bf[j] = *reinterpret_cast<const short8*>(&Bs[wn * 64 + j * 16 + l15][quad * 8]);
    #pragma unroll
    for (int i = 0; i < 4; ++i)
      #pragma unroll
      for (int j = 0; j < 4; ++j)
        acc[i][j] = __builtin_amdgcn_mfma_f32_16x16x32_bf16(af[i], bf[j], acc[i][j], 0, 0, 0);
    __syncthreads();
  }

  #pragma unroll
  for (int j = 0; j < 4; ++j) {
    const int n = n0 + wn * 64 + j * 16 + l15;
    const float bv = lin(bias, n, f32);
    #pragma unroll
    for (int i = 0; i < 4; ++i) {
      #pragma unroll
      for (int r = 0; r < 4; ++r) {
        const int m = m0 + wm * 64 + i * 16 + quad * 4 + r;
        float v = acc[i][j][r];
        if constexpr (MODE == M_BIAS) {
          v += bv;
        } else if constexpr (MODE == M_BIAS_RELU) {
          v = fmaxf(v + bv, 0.f);
        } else {
          float ad;
          if constexpr (sizeof(ADT) == 4) ad = ((const float*)addend)[(size_t)m * Nn + n];
          else                            ad = b2f(((const ushort*)addend)[(size_t)m * Nn + n]);
          v = ad + v + bv;
          if constexpr (MODE == M_ADD_BIAS_ELU)   v = (v > 0.f) ? v : expm1f(v);
          else if constexpr (MODE == M_ADD_BIAS_LEAKY) v = (v >= 0.f) ? v : 0.5f * v;
        }
        if constexpr (sizeof(OT) == 4) ((float*)Cout)[(size_t)m * Nn + n] = v;
        else                           ((ushort*)Cout)[(size_t)m * Nn + n] = f2b(v);
      }
    }
  }
}

template<typename ADT, typename OT, int MODE>
static void launch_mgemm(const void* A, const void* Wt, const void* bias, const void* add,
                         void* Cout, int M, int K, int Nn, const int* dtf, hipStream_t stream)
{
  dim3 grid(Nn / 128, M / 128);
  mgemm_kernel<ADT, OT, MODE><<<grid, dim3(256), 0, stream>>>(
      (const ushort*)A, (const ushort*)Wt, bias, (const ADT*)add, (OT*)Cout, M, K, Nn, dtf);
}

// ---------------- GAttn: wave-per-row top-k masked softmax attention -------
// grid (CC/4, HH, BPC), block 256 = 4 waves; wave w handles row l0+w.
// q row in LDS (broadcast float4 reads, low VGPR); kt stride 68 (b128,
// measured conflict-free); ww float4. c8 loop NOT unrolled.
template<typename OT>
__global__ __launch_bounds__(256) void gattn_kernel(
    const float* __restrict__ q, const float* __restrict__ k,
    const float* __restrict__ v, OT* __restrict__ out)
{
  const int tid = threadIdx.x;
  const int wave = tid >> 6, lane = tid & 63;
  const int l0 = blockIdx.x * 4;
  const int h = blockIdx.y, bz = blockIdx.z;
  const int l = l0 + wave;
  const size_t base = ((size_t)bz * CC) * DD + h * EE;

  __shared__ __align__(16) float kt[64][68];
  __shared__ __align__(16) float qs[4][64];
  __shared__ __align__(16) float ww[4][512];

  // wave-local q row staging (same wave writes & reads -> no block barrier)
  qs[wave][lane] = q[((size_t)bz * CC + l) * DD + h * EE + lane];

  float sc[8];
  const int sl = tid >> 4;            // 0..15
  const int e4 = (tid & 15) * 4;      // 0..60
  for (int c8 = 0; c8 < 8; ++c8) {    // NOT unrolled (VGPR budget)
    #pragma unroll
    for (int r = 0; r < 4; ++r) {
      const int s_local = sl + r * 16;
      const float4 kv = *reinterpret_cast<const float4*>(
          k + base + (size_t)(c8 * 64 + s_local) * DD + e4);
      *reinterpret_cast<float4*>(&kt[s_local][e4]) = kv;
    }
    __syncthreads();
    float a = 0.f;
    #pragma unroll
    for (int e = 0; e < 16; ++e) {
      const float4 qv = *reinterpret_cast<const float4*>(&qs[wave][e * 4]);  // broadcast
      const float4 kv = *reinterpret_cast<const float4*>(&kt[lane][e * 4]);
      a += qv.x * kv.x + qv.y * kv.y + qv.z * kv.z + qv.w * kv.w;
    }
    sc[c8] = a;
    __syncthreads();
  }

  // top-10 via wave shuffles
  float wk[8];
  #pragma unroll
  for (int j = 0; j < 8; ++j) wk[j] = sc[j];
  float maxv = 0.f, thr = 0.f;
  for (int it = 0; it < 10; ++it) {
    float lm = wk[0];
    #pragma unroll
    for (int j = 1; j < 8; ++j) lm = fmaxf(lm, wk[j]);
    float gm = lm;
    #pragma unroll
    for (int off = 32; off > 0; off >>= 1) gm = fmaxf(gm, __shfl_xor(gm, off));
    if (it == 0) maxv = gm;
    if (it == 9) { thr = gm; break; }
    const unsigned long long msk = __ballot(lm == gm);
    if (lane == __ffsll(msk) - 1) {
      #pragma unroll
      for (int j = 0; j < 8; ++j) { if (wk[j] == gm) { wk[j] = -FLT_MAX; break; } }
    }
  }

  float lsum = 0.f;
  #pragma unroll
  for (int j = 0; j < 8; ++j) {
    const float p = (sc[j] >= thr) ? expf((sc[j] - maxv) * 0.125f) : 0.f;
    ww[wave][j * 64 + lane] = p;
    lsum += p;
  }
  #pragma unroll
  for (int off = 32; off > 0; off >>= 1) lsum += __shfl_xor(lsum, off);
  const float inv = 1.f / lsum;
  __syncthreads();

  // A @ v: lane owns e = lane; ww read as float4 broadcasts
  float acc = 0.f;
  const float* vp = v + base + lane;
  const float* wp = ww[wave];
  for (int s = 0; s < 512; s += 4) {
    const float4 w4 = *reinterpret_cast<const float4*>(&wp[s]);
    acc = fmaf(w4.x, vp[(size_t)(s + 0) * DD], acc);
    acc = fmaf(w4.y, vp[(size_t)(s + 1) * DD], acc);
    acc = fmaf(w4.z, vp[(size_t)(s + 2) * DD], acc);
    acc = fmaf(w4.w, vp[(size_t)(s + 3) * DD], acc);
  }
  const float res = acc * inv;
  const size_t oi = ((size_t)bz * CC + l) * DD + h * EE + lane;
  if constexpr (sizeof(OT) == 4) out[oi] = res;
  else                           out[oi] = f2b(res);
}

// ---------------- pwattn1 (seq=512, pred=2048) ----------------
__global__ __launch_bounds__(128) void pwattn1_kernel(
    const ushort* __restrict__ query, const float* __restrict__ k1,
    const float* __restrict__ v1, ushort* __restrict__ V1)
{
  const int n = blockIdx.x, tid = threadIdx.x;
  __shared__ float ks[512], vs[512];
  __shared__ float Am[128][33];
  for (int i = tid; i < 512; i += 128) { ks[i] = k1[(size_t)n * 512 + i]; vs[i] = v1[(size_t)n * 512 + i]; }
  __syncthreads();
  {
    const int l = tid;
    float qv[16];
    const ushort* qp = query + (size_t)n * DFF + l * 16;
    #pragma unroll
    for (int e = 0; e < 16; ++e) qv[e] = b2f(qp[e]);
    float scl[32], mx = -FLT_MAX;
    #pragma unroll
    for (int s = 0; s < 32; ++s) {
      float a = 0.f;
      #pragma unroll
      for (int e = 0; e < 16; ++e) a += qv[e] * ks[s * 16 + e];
      scl[s] = a; mx = fmaxf(mx, a);
    }
    float sum = 0.f;
    #pragma unroll
    for (int s = 0; s < 32; ++s) { const float p = expf((scl[s] - mx) * 0.25f); scl[s] = p; sum += p; }
    const float invs = 1.f / sum;
    #pragma unroll
    for (int s = 0; s < 32; ++s) Am[l][s] = scl[s] * invs;
  }
  __syncthreads();
  #pragma unroll
  for (int r = 0; r < 16; ++r) {
    const int idx = tid + 128 * r;
    const int l = idx >> 4, e = idx & 15;
    float a = 0.f;
    #pragma unroll
    for (int s = 0; s < 32; ++s) a += Am[l][s] * vs[s * 16 + e];
    V1[(size_t)n * DFF + idx] = f2b(a);
  }
}

// ---------------- LayerNorm over 2048, in-place bf16 ----------------
__global__ __launch_bounds__(256) void ln_kernel(
    ushort* __restrict__ h, const void* __restrict__ g, const void* __restrict__ bt,
    const int* __restrict__ dtf)
{
  const int f32 = *dtf;
  const int n = blockIdx.x, tid = threadIdx.x;
  ushort* hp = h + (size_t)n * DFF;
  float x[8]; float s = 0.f, s2 = 0.f;
  #pragma unroll
  for (int i = 0; i < 8; ++i) {
    const float xv = b2f(hp[tid + 256 * i]);
    x[i] = xv; s += xv; s2 += xv * xv;
  }
  __shared__ float rs[256], rq[256];
  rs[tid] = s; rq[tid] = s2;
  __syncthreads();
  for (int off = 128; off > 0; off >>= 1) {
    if (tid < off) { rs[tid] += rs[tid + off]; rq[tid] += rq[tid + off]; }
    __syncthreads();
  }
  const float mu  = rs[0] * (1.f / DFF);
  const float var = rq[0] * (1.f / DFF) - mu * mu;
  const float inv = rsqrtf(var + 1e-5f);
  #pragma unroll
  for (int i = 0; i < 8; ++i) {
    const int d = tid + 256 * i;
    hp[d] = f2b((x[i] - mu) * inv * lin(g, d, f32) + lin(bt, d, f32));
  }
}

// ---------------- pwattn2 (seq=2048, pred=512), templated output -----------
template<typename OT>
__global__ __launch_bounds__(128) void pwattn2_kernel(
    const float* __restrict__ query2, const ushort* __restrict__ k2,
    const ushort* __restrict__ v2, OT* __restrict__ V2)
{
  const int n = blockIdx.x, tid = threadIdx.x;
  __shared__ float ks[2048], vs[2048];
  __shared__ float Am[32][129];
  for (int i = tid; i < 2048; i += 128) {
    ks[i] = b2f(k2[(size_t)n * DFF + i]);
    vs[i] = b2f(v2[(size_t)n * DFF + i]);
  }
  __syncthreads();
  if (tid < 32) {
    const int l = tid;
    float qv[16];
    #pragma unroll
    for (int e = 0; e < 16; ++e) qv[e] = query2[(size_t)n * 512 + l * 16 + e];
    float mx = -FLT_MAX;
    for (int s = 0; s < 128; ++s) {
      float a = 0.f;
      #pragma unroll
      for (int e = 0; e < 16; ++e) a += qv[e] * ks[s * 16 + e];
      Am[l][s] = a; mx = fmaxf(mx, a);
    }
    float sum = 0.f;
    for (int s = 0; s < 128; ++s) { const float p = expf((Am[l][s] - mx) * 0.25f); Am[l][s] = p; sum += p; }
    const float invs = 1.f / sum;
    for (int s = 0; s < 128; ++s) Am[l][s] *= invs;
  }
  __syncthreads();
  #pragma unroll
  for (int r = 0; r < 4; ++r) {
    const int idx = tid + 128 * r;
    const int l = idx >> 4, e = idx & 15;
    float a = 0.f;
    for (int s = 0; s < 128; ++s) a += Am[l][s] * vs[s * 16 + e];
    if constexpr (sizeof(OT) == 4) V2[(size_t)n * 512 + idx] = a;
    else                           V2[(size_t)n * 512 + idx] = f2b(a);
  }
}

// ---------------- final: dec = y@fc_w + fc_b; out = dec*std+mean -----------
__global__ __launch_bounds__(128) void final_kernel(
    const float* __restrict__ y, const void* __restrict__ fc_w,
    const void* __restrict__ fc_b, const float* __restrict__ meanb,
    const float* __restrict__ stdb, void* __restrict__ out, int row_base,
    const int* __restrict__ dtf)
{
  const int f32 = *dtf;
  const int row = row_base + blockIdx.x;
  const int b = row >> 9, c = row & 511;
  const int tid = threadIdx.x;
  __shared__ float yr[512];
  for (int i = tid; i < 512; i += 128) yr[i] = y[(size_t)blockIdx.x * 512 + i];
  __syncthreads();
  if (tid < PRED) {
    float a = 0.f;
    for (int d = 0; d < 512; ++d) a += yr[d] * lin(fc_w, d * PRED + tid, f32);
    a += lin(fc_b, tid, f32);
    const float r = a * stdb[row] + meanb[row];
    const size_t oi = ((size_t)b * PRED + tid) * CC + c;
    if (f32) ((float*)out)[oi] = r;
    else     ((ushort*)out)[oi] = f2b(r);
  }
}

// ---------------------------------------------------------------------------
extern "C" void kernel_launch(void* const* d_in, const int* in_sizes, int n_in,
                              void* d_out, int out_size, void* d_ws, size_t ws_size,
                              hipStream_t stream)
{
  (void)in_sizes; (void)n_in; (void)out_size;
  const void* x_enc   = d_in[0];
  const void* embed_w = d_in[4];
  const void* q_w = d_in[5],  * q_b = d_in[6];
  const void* k_w = d_in[7],  * k_b = d_in[8];
  const void* v_w = d_in[9],  * v_b = d_in[10];
  const void* o_w = d_in[11], * o_b = d_in[12];
  const void* enc_w = d_in[13], * enc_b = d_in[14];
  const void* f1q_w = d_in[15], * f1q_b = d_in[16];
  const void* f1k_w = d_in[17], * f1k_b = d_in[18];
  const void* f1v_w = d_in[19], * f1v_b = d_in[20];
  const void* f1o_w = d_in[21], * f1o_b = d_in[22];
  const void* f2q_w = d_in[23], * f2q_b = d_in[24];
  const void* f2k_w = d_in[25], * f2k_b = d_in[26];
  const void* f2v_w = d_in[27], * f2v_b = d_in[28];
  const void* f2o_w = d_in[29], * f2o_b = d_in[30];
  const void* ln_g  = d_in[31], * ln_b  = d_in[32];
  const void* fc_w  = d_in[33], * fc_b  = d_in[34];

  const size_t HDR = 131072 + 1024;
  const size_t E_F1Q = 512ull * 2048, E_F1O = 2048ull * 2048, E_F2Q = 2048ull * 512;
  const size_t E_F2K = 2048ull * 2048, E_F2V = 2048ull * 2048, E_F2O = 512ull * 512;
  const size_t E_SQ  = 512ull * 512;   // o_w, enc_w, f1k_w, f1v_w each
  const size_t WT_EL = E_F1Q + E_F1O + E_F2Q + E_F2K + E_F2V + E_F2O + 4 * E_SQ;
  const size_t WT_BYTES = WT_EL * 2;   // ~30.5 MB
  const size_t PER_BATCH = 5ull * 512 * 512 * 4 + 3ull * 512 * DFF * 2; // 11.53MB

  const int use_mfma = (HDR + WT_BYTES + PER_BATCH <= ws_size) ? 1 : 0;
  const size_t FIXED = HDR + (use_mfma ? WT_BYTES : 0);
  int BPC = 1;
  for (int c = 8; c >= 1; c >>= 1) {
    if (FIXED + (size_t)c * PER_BATCH <= ws_size) { BPC = c; break; }
  }
  const int R = BPC * 512;

  char* ws = (char*)d_ws;
  float* meanb = (float*)ws;
  float* stdb  = (float*)(ws + 65536);
  int*   dtf   = (int*)(ws + 131072);
  ushort* wt_base = (ushort*)(ws + HDR);
  ushort* wt_f1q = wt_base;
  ushort* wt_f1o = wt_f1q + E_F1Q;
  ushort* wt_f2q = wt_f1o + E_F1O;
  ushort* wt_f2k = wt_f2q + E_F2Q;
  ushort* wt_f2v = wt_f2k + E_F2K;
  ushort* wt_f2o = wt_f2v + E_F2V;
  ushort* wt_o   = wt_f2o + E_F2O;
  ushort* wt_enc = wt_o   + E_SQ;
  ushort* wt_f1k = wt_enc + E_SQ;
  ushort* wt_f1v = wt_f1k + E_SQ;
  char* arena = ws + FIXED;
  const size_t FSL = (size_t)R * 512 * 4;
  const size_t GSL = (size_t)R * DFF * 2;
  void* A_ = arena;
  void* B_ = arena + FSL;
  void* C_ = arena + 2 * FSL;
  void* D_ = arena + 3 * FSL;
  void* E_ = arena + 4 * FSL;
  void* G1 = arena + 5 * FSL;
  void* G2 = arena + 5 * FSL + GSL;
  void* G3 = arena + 5 * FSL + 2 * GSL;

  detect_dtype<<<1, 256, 0, stream>>>((const ushort*)x_enc, dtf);
  instnorm_stats<<<dim3(2, NB), 256, 0, stream>>>(x_enc, meanb, stdb, dtf);

  if (use_mfma) {   // one-time weight convert+transpose (KxN -> bf16 NxK)
    transpose_w<<<dim3(DFF / 32, 512 / 32), 256, 0, stream>>>(f1q_w, wt_f1q, 512, DFF, dtf);
    transpose_w<<<dim3(DFF / 32, DFF / 32), 256, 0, stream>>>(f1o_w, wt_f1o, DFF, DFF, dtf);
    transpose_w<<<dim3(512 / 32, DFF / 32), 256, 0, stream>>>(f2q_w, wt_f2q, DFF, 512, dtf);
    transpose_w<<<dim3(DFF / 32, DFF / 32), 256, 0, stream>>>(f2k_w, wt_f2k, DFF, DFF, dtf);
    transpose_w<<<dim3(DFF / 32, DFF / 32), 256, 0, stream>>>(f2v_w, wt_f2v, DFF, DFF, dtf);
    transpose_w<<<dim3(512 / 32, 512 / 32), 256, 0, stream>>>(f2o_w, wt_f2o, 512, 512, dtf);
    transpose_w<<<dim3(512 / 32, 512 / 32), 256, 0, stream>>>(o_w,   wt_o,   512, 512, dtf);
    transpose_w<<<dim3(512 / 32, 512 / 32), 256, 0, stream>>>(enc_w, wt_enc, 512, 512, dtf);
    transpose_w<<<dim3(512 / 32, 512 / 32), 256, 0, stream>>>(f1k_w, wt_f1k, 512, 512, dtf);
    transpose_w<<<dim3(512 / 32, 512 / 32), 256, 0, stream>>>(f1v_w, wt_f1v, 512, 512, dtf);
  }

  for (int bc = 0; bc < NB / BPC; ++bc) {
    const int b0 = bc * BPC;
    // --- stage 1 (fp32: feeds top-k mask) ---
    norm_transpose<<<dim3(16, 16, BPC), 256, 0, stream>>>(x_enc, meanb, stdb, (float*)A_, b0, dtf);
    launch_gemm<float, float, float, M_RELU_PE >(A_, embed_w, nullptr, nullptr, B_, R, 512, 512, dtf, stream); // emb
    launch_gemm<float, float, float, M_BIAS_RELU>(B_, q_w, q_b, nullptr, C_, R, 512, 512, dtf, stream);        // q
    launch_gemm<float, float, float, M_BIAS     >(B_, k_w, k_b, nullptr, D_, R, 512, 512, dtf, stream);        // k
    launch_gemm<float, float, float, M_BIAS_RELU>(B_, v_w, v_b, nullptr, E_, R, 512, 512, dtf, stream);        // v

    if (use_mfma) {
      gattn_kernel<ushort><<<dim3(CC / 4, HH, BPC), 256, 0, stream>>>(
          (float*)C_, (float*)D_, (float*)E_, (ushort*)A_);                                          // attn bf16
      launch_mgemm<float, ushort, M_ADD_BIAS_LEAKY>(A_, wt_o, o_b, B_, C_, R, 512, 512, dtf, stream); // y bf16
      launch_mgemm<float, ushort, M_BIAS>(C_, wt_enc, enc_b, nullptr, D_, R, 512, 512, dtf, stream);  // X1 bf16
      // --- stage 2: pwattn1 + LN ---
      launch_mgemm<float, ushort, M_BIAS_RELU>(D_, wt_f1q, f1q_b, nullptr, G1, R, 512, DFF, dtf, stream); // query1
      launch_mgemm<float, float,  M_BIAS     >(D_, wt_f1k, f1k_b, nullptr, A_, R, 512, 512, dtf, stream); // k1 f32
      launch_mgemm<float, float,  M_BIAS_RELU>(D_, wt_f1v, f1v_b, nullptr, B_, R, 512, 512, dtf, stream); // v1 f32
      pwattn1_kernel<<<R, 128, 0, stream>>>((const ushort*)G1, (const float*)A_, (const float*)B_, (ushort*)G2);
      launch_mgemm<ushort, ushort, M_ADD_BIAS_ELU>(G2, wt_f1o, f1o_b, G1, G1, R, DFF, DFF, dtf, stream);  // h
      ln_kernel<<<R, 256, 0, stream>>>((ushort*)G1, ln_g, ln_b, dtf);
      // --- stage 3: pwattn2 + out ---
      launch_mgemm<float, float,  M_BIAS_RELU>(G1, wt_f2q, f2q_b, nullptr, A_, R, DFF, 512, dtf, stream); // query2
      launch_mgemm<float, ushort, M_BIAS     >(G1, wt_f2k, f2k_b, nullptr, G2, R, DFF, DFF, dtf, stream); // k2
      launch_mgemm<float, ushort, M_BIAS_RELU>(G1, wt_f2v, f2v_b, nullptr, G3, R, DFF, DFF, dtf, stream); // v2
      pwattn2_kernel<ushort><<<R, 128, 0, stream>>>((const float*)A_, (const ushort*)G2, (const ushort*)G3, (ushort*)B_);
      launch_mgemm<float, float, M_ADD_BIAS>(B_, wt_f2o, f2o_b, A_, C_, R, 512, 512, dtf, stream);        // y2
    } else {
      gattn_kernel<float><<<dim3(CC / 4, HH, BPC), 256, 0, stream>>>(
          (float*)C_, (float*)D_, (float*)E_, (float*)A_);
      launch_gemm<float, float, float, M_ADD_BIAS_LEAKY>(A_, o_w, o_b, B_, C_, R, 512, 512, dtf, stream);
      launch_gemm<float, float, float, M_BIAS>(C_, enc_w, enc_b, nullptr, D_, R, 512, 512, dtf, stream);
      launch_gemm<float, float, ushort, M_BIAS_RELU>(D_, f1q_w, f1q_b, nullptr, G1, R, 512, DFF, dtf, stream);
      launch_gemm<float, float, float,  M_BIAS     >(D_, f1k_w, f1k_b, nullptr, A_, R, 512, 512, dtf, stream);
      launch_gemm<float, float, float,  M_BIAS_RELU>(D_, f1v_w, f1v_b, nullptr, B_, R, 512, 512, dtf, stream);
      pwattn1_kernel<<<R, 128, 0, stream>>>((const ushort*)G1, (const float*)A_, (const float*)B_, (ushort*)G2);
      launch_gemm<ushort, ushort, ushort, M_ADD_BIAS_ELU>(G2, f1o_w, f1o_b, G1, G1, R, DFF, DFF, dtf, stream);
      ln_kernel<<<R, 256, 0, stream>>>((ushort*)G1, ln_g, ln_b, dtf);
      launch_gemm<ushort, float, float,  M_BIAS_RELU>(G1, f2q_w, f2q_b, nullptr, A_, R, DFF, 512, dtf, stream);
      launch_gemm<ushort, float, ushort, M_BIAS     >(G1, f2k_w, f2k_b, nullptr, G2, R, DFF, DFF, dtf, stream);
      launch_gemm<ushort, float, ushort, M_BIAS_RELU>(G1, f2v_w, f2v_b, nullptr, G3, R, DFF, DFF, dtf, stream);
      pwattn2_kernel<float><<<R, 128, 0, stream>>>((const float*)A_, (const ushort*)G2, (const ushort*)G3, (float*)B_);
      launch_gemm<float, float, float, M_ADD_BIAS>(B_, f2o_w, f2o_b, A_, C_, R, 512, 512, dtf, stream);
    }
    final_kernel<<<R, 128, 0, stream>>>((const float*)C_, fc_w, fc_b, meanb, stdb, d_out, b0 * 512, dtf);
  }
}

// Round 11
// 3962.256 us; speedup vs baseline: 1.3924x; 1.0680x over previous
//
#include <hip/hip_runtime.h>
#include <float.h>
#include <math.h>
#include <stdint.h>

// ---------------------------------------------------------------------------
// Model_33062658245168: Informer-style time-series model. fp32 in/out
// (runtime-detected; bf16 fallback kept). B=32 S=512 C=512 D=512 DF=2048 H=8
// E=64 P=16 PRED=96 K(topk)=10, N=16384.
//
// Round 11: MFMA GAttn. Round-10 gattn was LDS-issue bound (~420 b128/wave
// at ~12cyc = the whole 222us). QK^T and PV are matmul-shaped -> MFMA:
//  - scores via bf16 hi/lo split (3 MFMAs) => ~1e-4 score error, top-k safe
//  - S (16x512 fp32) in LDS; shuffle top-k per row (proven code)
//  - P bf16 aliases S region (barrier-separated); PV = P @ V^T via MFMA
// LDS 49.3KB -> 3 blocks/CU. Layouts = m89-verified mgemm conventions.
// ---------------------------------------------------------------------------

#define NB   32
#define SS   512
#define CC   512
#define DD   512
#define DFF  2048
#define HH   8
#define EE   64
#define PRED 96

typedef __attribute__((ext_vector_type(8))) short short8;
typedef __attribute__((ext_vector_type(4))) float f32x4;

__device__ __forceinline__ float b2f(ushort u) {
  union { float f; uint32_t i; } c; c.i = ((uint32_t)u) << 16; return c.f;
}
__device__ __forceinline__ ushort f2b(float f) {
  union { float f; uint32_t i; } c; c.f = f;
  uint32_t x = c.i;
  return (ushort)((x + 0x7fffu + ((x >> 16) & 1u)) >> 16);   // RNE
}
__device__ __forceinline__ float lin(const void* p, size_t i, int f32) {
  return f32 ? ((const float*)p)[i] : b2f(((const ushort*)p)[i]);
}
__device__ __forceinline__ void split_bf(float x, ushort& hi, ushort& lo) {
  hi = f2b(x);
  lo = f2b(x - b2f(hi));
}

// ---------------- dtype detection (1 = fp32 inputs) ----------------
__global__ __launch_bounds__(256) void detect_dtype(
    const ushort* __restrict__ x, int* __restrict__ flag)
{
  __shared__ float red[256];
  const int t = threadIdx.x;
  float v = fabsf(b2f(x[2 * t]));
  if (!(v < 1e30f)) v = 1e30f;
  red[t] = v;
  __syncthreads();
  for (int off = 128; off > 0; off >>= 1) {
    if (t < off) red[t] = fmaxf(red[t], red[t + off]);
    __syncthreads();
  }
  if (t == 0) flag[0] = (red[0] > 1e6f) ? 1 : 0;
}

// ---------------- instance norm stats ----------------
__global__ __launch_bounds__(256) void instnorm_stats(
    const void* __restrict__ x, float* __restrict__ meanb, float* __restrict__ stdb,
    const int* __restrict__ dtf)
{
  const int f32 = *dtf;
  const int c = blockIdx.x * 256 + threadIdx.x;
  const int b = blockIdx.y;
  float s = 0.f, s2 = 0.f;
  for (int t = 0; t < SS; ++t) {
    const float xv = lin(x, ((size_t)(b * SS) + t) * CC + c, f32);
    s += xv; s2 += xv * xv;
  }
  const float mu  = s * (1.f / SS);
  const float var = s2 * (1.f / SS) - mu * mu;
  meanb[b * CC + c] = mu;
  stdb [b * CC + c] = sqrtf(var + 1e-5f);
}

// ---------------- normalize + transpose one chunk ----------------
__global__ __launch_bounds__(256) void norm_transpose(
    const void* __restrict__ x, const float* __restrict__ meanb,
    const float* __restrict__ stdb, float* __restrict__ xTc, int b_base,
    const int* __restrict__ dtf)
{
  const int f32 = *dtf;
  __shared__ float t[32][33];
  const int s0 = blockIdx.x * 32, c0 = blockIdx.y * 32, lb = blockIdx.z;
  const int b = b_base + lb;
  const int tx = threadIdx.x & 31, ty = threadIdx.x >> 5;
  #pragma unroll
  for (int i = 0; i < 4; ++i) {
    const int s = s0 + ty + i * 8;
    t[ty + i * 8][tx] = lin(x, ((size_t)(b * SS) + s) * CC + c0 + tx, f32);
  }
  __syncthreads();
  #pragma unroll
  for (int i = 0; i < 4; ++i) {
    const int c = c0 + ty + i * 8;
    const float mu = meanb[b * CC + c], sd = stdb[b * CC + c];
    xTc[((size_t)(lb * CC) + c) * SS + s0 + tx] = (t[tx][ty + i * 8] - mu) / sd;
  }
}

// ---------------- weight convert+transpose: W (KxN, input dtype) -> bf16 (NxK)
__global__ __launch_bounds__(256) void transpose_w(
    const void* __restrict__ W, ushort* __restrict__ Wt, int K, int N,
    const int* __restrict__ dtf)
{
  const int f32 = *dtf;
  __shared__ float t[32][33];
  const int n0 = blockIdx.x * 32, k0 = blockIdx.y * 32;
  const int tx = threadIdx.x & 31, ty = threadIdx.x >> 5;
  #pragma unroll
  for (int i = 0; i < 4; ++i)
    t[ty + i * 8][tx] = lin(W, (size_t)(k0 + ty + i * 8) * N + n0 + tx, f32);
  __syncthreads();
  #pragma unroll
  for (int i = 0; i < 4; ++i)
    Wt[(size_t)(n0 + ty + i * 8) * K + k0 + tx] = f2b(t[tx][ty + i * 8]);
}

// ---------------- generic fp32 tiled GEMM (stage-1 + fallback) ----------
enum GemmMode { M_BIAS = 0, M_BIAS_RELU = 1, M_RELU_PE = 2,
                M_ADD_BIAS_LEAKY = 3, M_ADD_BIAS_ELU = 4, M_ADD_BIAS = 5 };

template<typename AT, typename ADT, typename OT, int MODE>
__global__ __launch_bounds__(256) void gemm_kernel(
    const AT* __restrict__ A, const void* __restrict__ Bw,
    const void* __restrict__ bias, const ADT* __restrict__ addend,
    OT* __restrict__ Cout, int M, int K, int Nn, const int* __restrict__ dtf)
{
  const int f32 = *dtf;
  __shared__ __align__(16) float As[16][68];
  __shared__ __align__(16) float Bs[16][68];
  const int tid = threadIdx.x;
  const int m0 = blockIdx.y * 64, n0 = blockIdx.x * 64;
  const int tx = tid & 15, ty = tid >> 4;
  const int la_m = tid >> 2, la_k = (tid & 3) * 4;
  const int lb_k = tid >> 4, lb_n = (tid & 15) * 4;
  float acc[4][4];
  #pragma unroll
  for (int i = 0; i < 4; ++i)
    #pragma unroll
    for (int j = 0; j < 4; ++j) acc[i][j] = 0.f;
  const size_t a_row = (size_t)(m0 + la_m) * K;

  for (int k0 = 0; k0 < K; k0 += 16) {
    if constexpr (sizeof(AT) == 4) {
      const float4 av = *reinterpret_cast<const float4*>(A + a_row + k0 + la_k);
      As[la_k + 0][la_m] = av.x; As[la_k + 1][la_m] = av.y;
      As[la_k + 2][la_m] = av.z; As[la_k + 3][la_m] = av.w;
    } else {
      const ushort4 av = *reinterpret_cast<const ushort4*>(A + a_row + k0 + la_k);
      As[la_k + 0][la_m] = b2f(av.x); As[la_k + 1][la_m] = b2f(av.y);
      As[la_k + 2][la_m] = b2f(av.z); As[la_k + 3][la_m] = b2f(av.w);
    }
    {
      const size_t boff = (size_t)(k0 + lb_k) * Nn + n0 + lb_n;
      if (f32) {
        const float4 bv = *reinterpret_cast<const float4*>((const float*)Bw + boff);
        Bs[lb_k][lb_n + 0] = bv.x; Bs[lb_k][lb_n + 1] = bv.y;
        Bs[lb_k][lb_n + 2] = bv.z; Bs[lb_k][lb_n + 3] = bv.w;
      } else {
        const ushort4 bv = *reinterpret_cast<const ushort4*>((const ushort*)Bw + boff);
        Bs[lb_k][lb_n + 0] = b2f(bv.x); Bs[lb_k][lb_n + 1] = b2f(bv.y);
        Bs[lb_k][lb_n + 2] = b2f(bv.z); Bs[lb_k][lb_n + 3] = b2f(bv.w);
      }
    }
    __syncthreads();
    #pragma unroll
    for (int k = 0; k < 16; ++k) {
      const float4 a4 = *reinterpret_cast<const float4*>(&As[k][ty * 4]);
      const float4 b4 = *reinterpret_cast<const float4*>(&Bs[k][tx * 4]);
      const float aa[4] = {a4.x, a4.y, a4.z, a4.w};
      const float bb[4] = {b4.x, b4.y, b4.z, b4.w};
      #pragma unroll
      for (int i = 0; i < 4; ++i)
        #pragma unroll
        for (int j = 0; j < 4; ++j)
          acc[i][j] = fmaf(aa[i], bb[j], acc[i][j]);
    }
    __syncthreads();
  }

  float biasv[4];
  if constexpr (MODE != M_RELU_PE) {
    #pragma unroll
    for (int j = 0; j < 4; ++j) biasv[j] = lin(bias, n0 + tx * 4 + j, f32);
  }
  #pragma unroll
  for (int i = 0; i < 4; ++i) {
    const int m = m0 + ty * 4 + i;
    #pragma unroll
    for (int j = 0; j < 4; ++j) {
      const int n = n0 + tx * 4 + j;
      float v = acc[i][j];
      if constexpr (MODE == M_BIAS) {
        v += biasv[j];
      } else if constexpr (MODE == M_BIAS_RELU) {
        v = fmaxf(v + biasv[j], 0.f);
      } else if constexpr (MODE == M_RELU_PE) {
        v = fmaxf(v, 0.f);
        const float freq = expf((float)(n & ~1) * (-0.017988946f)); // -ln(1e4)/512
        const float ang  = (float)(m & (CC - 1)) * freq;            // pos = c
        v += (n & 1) ? cosf(ang) : sinf(ang);
      } else {
        float ad;
        if constexpr (sizeof(ADT) == 4) ad = ((const float*)addend)[(size_t)m * Nn + n];
        else                            ad = b2f(((const ushort*)addend)[(size_t)m * Nn + n]);
        v = ad + v + biasv[j];
        if constexpr (MODE == M_ADD_BIAS_LEAKY) v = (v >= 0.f) ? v : 0.5f * v;
        else if constexpr (MODE == M_ADD_BIAS_ELU) v = (v > 0.f) ? v : expm1f(v);
      }
      if constexpr (sizeof(OT) == 4) ((float*)Cout)[(size_t)m * Nn + n] = v;
      else                           ((ushort*)Cout)[(size_t)m * Nn + n] = f2b(v);
    }
  }
}

template<typename AT, typename ADT, typename OT, int MODE>
static void launch_gemm(const void* A, const void* Bw, const void* bias, const void* add,
                        void* Cout, int M, int K, int Nn, const int* dtf, hipStream_t stream)
{
  dim3 grid(Nn / 64, M / 64);
  gemm_kernel<AT, ADT, OT, MODE><<<grid, dim3(256), 0, stream>>>(
      (const AT*)A, Bw, bias, (const ADT*)add, (OT*)Cout, M, K, Nn, dtf);
}

// ---------------- MFMA bf16 GEMM: Cout = epi(A @ Wt^T) ----------------
template<typename ADT, typename OT, int MODE>
__global__ __launch_bounds__(256) void mgemm_kernel(
    const ushort* __restrict__ A, const ushort* __restrict__ Wt,
    const void* __restrict__ bias, const ADT* __restrict__ addend,
    OT* __restrict__ Cout, int M, int K, int Nn, const int* __restrict__ dtf)
{
  const int f32 = *dtf;
  __shared__ __align__(16) ushort As[128][40];
  __shared__ __align__(16) ushort Bs[128][40];
  const int tid = threadIdx.x;
  const int m0 = blockIdx.y * 128, n0 = blockIdx.x * 128;
  const int wave = tid >> 6, lane = tid & 63;
  const int wm = wave & 1, wn = wave >> 1;
  const int quad = lane >> 4, l15 = lane & 15;

  f32x4 acc[4][4];
  #pragma unroll
  for (int i = 0; i < 4; ++i)
    #pragma unroll
    for (int j = 0; j < 4; ++j) acc[i][j] = (f32x4){0.f, 0.f, 0.f, 0.f};

  const int srow = tid >> 1, sseg = (tid & 1) * 16;
  const size_t a_base = (size_t)(m0 + srow) * K + sseg;
  const size_t b_base = (size_t)(n0 + srow) * K + sseg;

  for (int k0 = 0; k0 < K; k0 += 32) {
    {
      const float4* ga = reinterpret_cast<const float4*>(A + a_base + k0);
      const float4* gb = reinterpret_cast<const float4*>(Wt + b_base + k0);
      const float4 a0 = ga[0], a1 = ga[1];
      const float4 b0 = gb[0], b1 = gb[1];
      float4* da = reinterpret_cast<float4*>(&As[srow][sseg]);
      float4* db = reinterpret_cast<float4*>(&Bs[srow][sseg]);
      da[0] = a0; da[1] = a1;
      db[0] = b0; db[1] = b1;
    }
    __syncthreads();
    short8 af[4], bf[4];
    #pragma unroll
    for (int i = 0; i < 4; ++i)
      af[i] = *reinterpret_cast<const short8*>(&As[wm * 64 + i * 16 + l15][quad * 8]);
    #pragma unroll
    for (int j = 0; j < 4; ++j)
      bf[j] = *reinterpret_cast<const short8*>(&Bs[wn * 64 + j * 16 + l15][quad * 8]);
    #pragma unroll
    for (int i = 0; i < 4; ++i)
      #pragma unroll
      for (int j = 0; j < 4; ++j)
        acc[i][j] = __builtin_amdgcn_mfma_f32_16x16x32_bf16(af[i], bf[j], acc[i][j], 0, 0, 0);
    __syncthreads();
  }

  #pragma unroll
  for (int j = 0; j < 4; ++j) {
    const int n = n0 + wn * 64 + j * 16 + l15;
    const float bv = lin(bias, n, f32);
    #pragma unroll
    for (int i = 0; i < 4; ++i) {
      #pragma unroll
      for (int r = 0; r < 4; ++r) {
        const int m = m0 + wm * 64 + i * 16 + quad * 4 + r;
        float v = acc[i][j][r];
        if constexpr (MODE == M_BIAS) {
          v += bv;
        } else if constexpr (MODE == M_BIAS_RELU) {
          v = fmaxf(v + bv, 0.f);
        } else {
          float ad;
          if constexpr (sizeof(ADT) == 4) ad = ((const float*)addend)[(size_t)m * Nn + n];
          else                            ad = b2f(((const ushort*)addend)[(size_t)m * Nn + n]);
          v = ad + v + bv;
          if constexpr (MODE == M_ADD_BIAS_ELU)   v = (v > 0.f) ? v : expm1f(v);
          else if constexpr (MODE == M_ADD_BIAS_LEAKY) v = (v >= 0.f) ? v : 0.5f * v;
        }
        if constexpr (sizeof(OT) == 4) ((float*)Cout)[(size_t)m * Nn + n] = v;
        else                           ((ushort*)Cout)[(size_t)m * Nn + n] = f2b(v);
      }
    }
  }
}

template<typename ADT, typename OT, int MODE>
static void launch_mgemm(const void* A, const void* Wt, const void* bias, const void* add,
                         void* Cout, int M, int K, int Nn, const int* dtf, hipStream_t stream)
{
  dim3 grid(Nn / 128, M / 128);
  mgemm_kernel<ADT, OT, MODE><<<grid, dim3(256), 0, stream>>>(
      (const ushort*)A, (const ushort*)Wt, bias, (const ADT*)add, (OT*)Cout, M, K, Nn, dtf);
}

// ---------------- GAttn via MFMA: 16 rows/block, one (b,h) -----------------
// grid (CC/16, HH, BPC), block 256 = 4 waves.
// S = Q K^T via bf16 hi/lo split (3 MFMAs, err ~1e-4); shuffle top-k per row;
// P bf16 aliases the S LDS region (barrier-separated); PV = P @ V^T MFMA.
__global__ __launch_bounds__(256) void gattn_mfma(
    const float* __restrict__ q, const float* __restrict__ k,
    const float* __restrict__ v, ushort* __restrict__ out)
{
  const int tid = threadIdx.x;
  const int wave = tid >> 6, lane = tid & 63;
  const int quad = lane >> 4, l15 = lane & 15;
  const int l0 = blockIdx.x * 16;
  const int h = blockIdx.y, bz = blockIdx.z;
  const size_t base = ((size_t)bz * CC) * DD + h * EE;

  __shared__ __align__(16) char smem[50496];
  float  (*S)[516]   = reinterpret_cast<float(*)[516]>(smem);          // 33024 B
  ushort (*P)[520]   = reinterpret_cast<ushort(*)[520]>(smem);         // aliases S
  ushort (*Qhi)[72]  = reinterpret_cast<ushort(*)[72]>(smem + 33024);  // 2304 B
  ushort (*Qlo)[72]  = reinterpret_cast<ushort(*)[72]>(smem + 35328);  // 2304 B
  ushort (*Khi)[40]  = reinterpret_cast<ushort(*)[40]>(smem + 37632);  // 5120 B
  ushort (*Klo)[40]  = reinterpret_cast<ushort(*)[40]>(smem + 42752);  // 5120 B
  ushort (*Vt)[136]  = reinterpret_cast<ushort(*)[136]>(smem + 33024); // aliases Q/K
  float*  sl         = reinterpret_cast<float*>(smem + 50432);         // 16 f32

  // ---- stage Q (16 rows x 64 e) as hi/lo bf16 ----
  {
    const int r = tid >> 4, e4 = (tid & 15) * 4;
    const float4 qv = *reinterpret_cast<const float4*>(
        q + ((size_t)bz * CC + l0 + r) * DD + h * EE + e4);
    ushort4 uh, ul;
    split_bf(qv.x, uh.x, ul.x); split_bf(qv.y, uh.y, ul.y);
    split_bf(qv.z, uh.z, ul.z); split_bf(qv.w, uh.w, ul.w);
    *reinterpret_cast<ushort4*>(&Qhi[r][e4]) = uh;
    *reinterpret_cast<ushort4*>(&Qlo[r][e4]) = ul;
  }

  // ---- S phase: 8 s-chunks of 64; wave w owns n-tile cols c*64+w*16+l15 ----
  const int ks_row = tid >> 2, ks_e8 = (tid & 3) * 8;   // K staging map
  for (int c = 0; c < 8; ++c) {
    f32x4 acc = (f32x4){0.f, 0.f, 0.f, 0.f};
    for (int kh = 0; kh < 2; ++kh) {
      __syncthreads();   // protect previous LDS reads before restage
      {
        const float4* kp = reinterpret_cast<const float4*>(
            k + base + (size_t)(c * 64 + ks_row) * DD + kh * 32 + ks_e8);
        const float4 k0v = kp[0], k1v = kp[1];
        ushort4 h0, h1, l0v, l1v;
        split_bf(k0v.x, h0.x, l0v.x); split_bf(k0v.y, h0.y, l0v.y);
        split_bf(k0v.z, h0.z, l0v.z); split_bf(k0v.w, h0.w, l0v.w);
        split_bf(k1v.x, h1.x, l1v.x); split_bf(k1v.y, h1.y, l1v.y);
        split_bf(k1v.z, h1.z, l1v.z); split_bf(k1v.w, h1.w, l1v.w);
        *reinterpret_cast<ushort4*>(&Khi[ks_row][ks_e8])     = h0;
        *reinterpret_cast<ushort4*>(&Khi[ks_row][ks_e8 + 4]) = h1;
        *reinterpret_cast<ushort4*>(&Klo[ks_row][ks_e8])     = l0v;
        *reinterpret_cast<ushort4*>(&Klo[ks_row][ks_e8 + 4]) = l1v;
      }
      __syncthreads();
      const short8 ah = *reinterpret_cast<const short8*>(&Qhi[l15][kh * 32 + quad * 8]);
      const short8 al = *reinterpret_cast<const short8*>(&Qlo[l15][kh * 32 + quad * 8]);
      const short8 bh = *reinterpret_cast<const short8*>(&Khi[wave * 16 + l15][quad * 8]);
      const short8 bl = *reinterpret_cast<const short8*>(&Klo[wave * 16 + l15][quad * 8]);
      acc = __builtin_amdgcn_mfma_f32_16x16x32_bf16(ah, bh, acc, 0, 0, 0);
      acc = __builtin_amdgcn_mfma_f32_16x16x32_bf16(ah, bl, acc, 0, 0, 0);
      acc = __builtin_amdgcn_mfma_f32_16x16x32_bf16(al, bh, acc, 0, 0, 0);
    }
    const int col = c * 64 + wave * 16 + l15;
    #pragma unroll
    for (int r = 0; r < 4; ++r) S[quad * 4 + r][col] = acc[r];
  }
  __syncthreads();   // all S visible

  // ---- top-k + softmax weights (wave w owns rows 4w..4w+3) ----
  float wts[4][8];
  #pragma unroll
  for (int r = 0; r < 4; ++r) {
    const int R = wave * 4 + r;
    float sc[8];
    #pragma unroll
    for (int j = 0; j < 8; ++j) sc[j] = S[R][j * 64 + lane];
    float wk[8];
    #pragma unroll
    for (int j = 0; j < 8; ++j) wk[j] = sc[j];
    float maxv = 0.f, thr = 0.f;
    for (int it = 0; it < 10; ++it) {
      float lm = wk[0];
      #pragma unroll
      for (int j = 1; j < 8; ++j) lm = fmaxf(lm, wk[j]);
      float gm = lm;
      #pragma unroll
      for (int off = 32; off > 0; off >>= 1) gm = fmaxf(gm, __shfl_xor(gm, off));
      if (it == 0) maxv = gm;
      if (it == 9) { thr = gm; break; }
      const unsigned long long msk = __ballot(lm == gm);
      if (lane == __ffsll(msk) - 1) {
        #pragma unroll
        for (int j = 0; j < 8; ++j) { if (wk[j] == gm) { wk[j] = -FLT_MAX; break; } }
      }
    }
    float lsum = 0.f;
    #pragma unroll
    for (int j = 0; j < 8; ++j) {
      const float p = (sc[j] >= thr) ? expf((sc[j] - maxv) * 0.125f) : 0.f;
      wts[r][j] = p; lsum += p;
    }
    #pragma unroll
    for (int off = 32; off > 0; off >>= 1) lsum += __shfl_xor(lsum, off);
    if (lane == 0) sl[R] = 1.f / lsum;
  }
  __syncthreads();   // all S reads done -> safe to overwrite with P

  #pragma unroll
  for (int r = 0; r < 4; ++r)
    #pragma unroll
    for (int j = 0; j < 8; ++j)
      P[wave * 4 + r][j * 64 + lane] = f2b(wts[r][j]);
  __syncthreads();

  // ---- PV phase: 4 s-chunks of 128; wave w owns e-cols w*16..w*16+15 ----
  f32x4 pacc = (f32x4){0.f, 0.f, 0.f, 0.f};
  const int vs = tid >> 1, veh = (tid & 1) * 32;   // V staging map
  for (int c = 0; c < 4; ++c) {
    __syncthreads();   // protect previous Vt reads (and Q/K region first time)
    {
      const float* vp = v + base + (size_t)(c * 128 + vs) * DD + veh;
      #pragma unroll
      for (int i = 0; i < 8; ++i) {
        const float4 vv = reinterpret_cast<const float4*>(vp)[i];
        const int e0 = veh + i * 4;
        Vt[e0 + 0][vs] = f2b(vv.x); Vt[e0 + 1][vs] = f2b(vv.y);
        Vt[e0 + 2][vs] = f2b(vv.z); Vt[e0 + 3][vs] = f2b(vv.w);
      }
    }
    __syncthreads();
    #pragma unroll
    for (int ks = 0; ks < 4; ++ks) {
      const short8 pa = *reinterpret_cast<const short8*>(&P[l15][c * 128 + ks * 32 + quad * 8]);
      const short8 vb = *reinterpret_cast<const short8*>(&Vt[wave * 16 + l15][ks * 32 + quad * 8]);
      pacc = __builtin_amdgcn_mfma_f32_16x16x32_bf16(pa, vb, pacc, 0, 0, 0);
    }
  }

  // ---- epilogue: out[row][h*64 + wave*16 + l15] = pacc * inv[row] ----
  #pragma unroll
  for (int r = 0; r < 4; ++r) {
    const int R = quad * 4 + r;
    const float res = pacc[r] * sl[R];
    out[((size_t)bz * CC + l0 + R) * DD + h * EE + wave * 16 + l15] = f2b(res);
  }
}

// ---------------- GAttn fallback (round-10 form, fp32 path only) -----------
template<typename OT>
__global__ __launch_bounds__(256) void gattn_fb(
    const float* __restrict__ q, const float* __restrict__ k,
    const float* __restrict__ v, OT* __restrict__ out)
{
  const int tid = threadIdx.x;
  const int wave = tid >> 6, lane = tid & 63;
  const int l0 = blockIdx.x * 4;
  const int h = blockIdx.y, bz = blockIdx.z;
  const int l = l0 + wave;
  const size_t base = ((size_t)bz * CC) * DD + h * EE;

  __shared__ __align__(16) float kt[64][68];
  __shared__ __align__(16) float qs[4][64];
  __shared__ __align__(16) float ww[4][512];

  qs[wave][lane] = q[((size_t)bz * CC + l) * DD + h * EE + lane];

  float sc[8];
  const int sl = tid >> 4;
  const int e4 = (tid & 15) * 4;
  for (int c8 = 0; c8 < 8; ++c8) {
    #pragma unroll
    for (int r = 0; r < 4; ++r) {
      const int s_local = sl + r * 16;
      const float4 kv = *reinterpret_cast<const float4*>(
          k + base + (size_t)(c8 * 64 + s_local) * DD + e4);
      *reinterpret_cast<float4*>(&kt[s_local][e4]) = kv;
    }
    __syncthreads();
    float a = 0.f;
    #pragma unroll
    for (int e = 0; e < 16; ++e) {
      const float4 qv = *reinterpret_cast<const float4*>(&qs[wave][e * 4]);
      const float4 kv = *reinterpret_cast<const float4*>(&kt[lane][e * 4]);
      a += qv.x * kv.x + qv.y * kv.y + qv.z * kv.z + qv.w * kv.w;
    }
    sc[c8] = a;
    __syncthreads();
  }

  float wk[8];
  #pragma unroll
  for (int j = 0; j < 8; ++j) wk[j] = sc[j];
  float maxv = 0.f, thr = 0.f;
  for (int it = 0; it < 10; ++it) {
    float lm = wk[0];
    #pragma unroll
    for (int j = 1; j < 8; ++j) lm = fmaxf(lm, wk[j]);
    float gm = lm;
    #pragma unroll
    for (int off = 32; off > 0; off >>= 1) gm = fmaxf(gm, __shfl_xor(gm, off));
    if (it == 0) maxv = gm;
    if (it == 9) { thr = gm; break; }
    const unsigned long long msk = __ballot(lm == gm);
    if (lane == __ffsll(msk) - 1) {
      #pragma unroll
      for (int j = 0; j < 8; ++j) { if (wk[j] == gm) { wk[j] = -FLT_MAX; break; } }
    }
  }

  float lsum = 0.f;
  #pragma unroll
  for (int j = 0; j < 8; ++j) {
    const float p = (sc[j] >= thr) ? expf((sc[j] - maxv) * 0.125f) : 0.f;
    ww[wave][j * 64 + lane] = p;
    lsum += p;
  }
  #pragma unroll
  for (int off = 32; off > 0; off >>= 1) lsum += __shfl_xor(lsum, off);
  const float inv = 1.f / lsum;
  __syncthreads();

  float acc = 0.f;
  const float* vp = v + base + lane;
  const float* wp = ww[wave];
  for (int s = 0; s < 512; s += 4) {
    const float4 w4 = *reinterpret_cast<const float4*>(&wp[s]);
    acc = fmaf(w4.x, vp[(size_t)(s + 0) * DD], acc);
    acc = fmaf(w4.y, vp[(size_t)(s + 1) * DD], acc);
    acc = fmaf(w4.z, vp[(size_t)(s + 2) * DD], acc);
    acc = fmaf(w4.w, vp[(size_t)(s + 3) * DD], acc);
  }
  const float res = acc * inv;
  const size_t oi = ((size_t)bz * CC + l) * DD + h * EE + lane;
  if constexpr (sizeof(OT) == 4) out[oi] = res;
  else                           out[oi] = f2b(res);
}

// ---------------- pwattn1 (seq=512, pred=2048) ----------------
__global__ __launch_bounds__(128) void pwattn1_kernel(
    const ushort* __restrict__ query, const float* __restrict__ k1,
    const float* __restrict__ v1, ushort* __restrict__ V1)
{
  const int n = blockIdx.x, tid = threadIdx.x;
  __shared__ float ks[512], vs[512];
  __shared__ float Am[128][33];
  for (int i = tid; i < 512; i += 128) { ks[i] = k1[(size_t)n * 512 + i]; vs[i] = v1[(size_t)n * 512 + i]; }
  __syncthreads();
  {
    const int l = tid;
    float qv[16];
    const ushort* qp = query + (size_t)n * DFF + l * 16;
    #pragma unroll
    for (int e = 0; e < 16; ++e) qv[e] = b2f(qp[e]);
    float scl[32], mx = -FLT_MAX;
    #pragma unroll
    for (int s = 0; s < 32; ++s) {
      float a = 0.f;
      #pragma unroll
      for (int e = 0; e < 16; ++e) a += qv[e] * ks[s * 16 + e];
      scl[s] = a; mx = fmaxf(mx, a);
    }
    float sum = 0.f;
    #pragma unroll
    for (int s = 0; s < 32; ++s) { const float p = expf((scl[s] - mx) * 0.25f); scl[s] = p; sum += p; }
    const float invs = 1.f / sum;
    #pragma unroll
    for (int s = 0; s < 32; ++s) Am[l][s] = scl[s] * invs;
  }
  __syncthreads();
  #pragma unroll
  for (int r = 0; r < 16; ++r) {
    const int idx = tid + 128 * r;
    const int l = idx >> 4, e = idx & 15;
    float a = 0.f;
    #pragma unroll
    for (int s = 0; s < 32; ++s) a += Am[l][s] * vs[s * 16 + e];
    V1[(size_t)n * DFF + idx] = f2b(a);
  }
}

// ---------------- LayerNorm over 2048, in-place bf16 ----------------
__global__ __launch_bounds__(256) void ln_kernel(
    ushort* __restrict__ h, const void* __restrict__ g, const void* __restrict__ bt,
    const int* __restrict__ dtf)
{
  const int f32 = *dtf;
  const int n = blockIdx.x, tid = threadIdx.x;
  ushort* hp = h + (size_t)n * DFF;
  float x[8]; float s = 0.f, s2 = 0.f;
  #pragma unroll
  for (int i = 0; i < 8; ++i) {
    const float xv = b2f(hp[tid + 256 * i]);
    x[i] = xv; s += xv; s2 += xv * xv;
  }
  __shared__ float rs[256], rq[256];
  rs[tid] = s; rq[tid] = s2;
  __syncthreads();
  for (int off = 128; off > 0; off >>= 1) {
    if (tid < off) { rs[tid] += rs[tid + off]; rq[tid] += rq[tid + off]; }
    __syncthreads();
  }
  const float mu  = rs[0] * (1.f / DFF);
  const float var = rq[0] * (1.f / DFF) - mu * mu;
  const float inv = rsqrtf(var + 1e-5f);
  #pragma unroll
  for (int i = 0; i < 8; ++i) {
    const int d = tid + 256 * i;
    hp[d] = f2b((x[i] - mu) * inv * lin(g, d, f32) + lin(bt, d, f32));
  }
}

// ---------------- pwattn2 (seq=2048, pred=512), templated output -----------
template<typename OT>
__global__ __launch_bounds__(128) void pwattn2_kernel(
    const float* __restrict__ query2, const ushort* __restrict__ k2,
    const ushort* __restrict__ v2, OT* __restrict__ V2)
{
  const int n = blockIdx.x, tid = threadIdx.x;
  __shared__ float ks[2048], vs[2048];
  __shared__ float Am[32][129];
  for (int i = tid; i < 2048; i += 128) {
    ks[i] = b2f(k2[(size_t)n * DFF + i]);
    vs[i] = b2f(v2[(size_t)n * DFF + i]);
  }
  __syncthreads();
  if (tid < 32) {
    const int l = tid;
    float qv[16];
    #pragma unroll
    for (int e = 0; e < 16; ++e) qv[e] = query2[(size_t)n * 512 + l * 16 + e];
    float mx = -FLT_MAX;
    for (int s = 0; s < 128; ++s) {
      float a = 0.f;
      #pragma unroll
      for (int e = 0; e < 16; ++e) a += qv[e] * ks[s * 16 + e];
      Am[l][s] = a; mx = fmaxf(mx, a);
    }
    float sum = 0.f;
    for (int s = 0; s < 128; ++s) { const float p = expf((Am[l][s] - mx) * 0.25f); Am[l][s] = p; sum += p; }
    const float invs = 1.f / sum;
    for (int s = 0; s < 128; ++s) Am[l][s] *= invs;
  }
  __syncthreads();
  #pragma unroll
  for (int r = 0; r < 4; ++r) {
    const int idx = tid + 128 * r;
    const int l = idx >> 4, e = idx & 15;
    float a = 0.f;
    for (int s = 0; s < 128; ++s) a += Am[l][s] * vs[s * 16 + e];
    if constexpr (sizeof(OT) == 4) V2[(size_t)n * 512 + idx] = a;
    else                           V2[(size_t)n * 512 + idx] = f2b(a);
  }
}

// ---------------- final: dec = y@fc_w + fc_b; out = dec*std+mean -----------
__global__ __launch_bounds__(128) void final_kernel(
    const float* __restrict__ y, const void* __restrict__ fc_w,
    const void* __restrict__ fc_b, const float* __restrict__ meanb,
    const float* __restrict__ stdb, void* __restrict__ out, int row_base,
    const int* __restrict__ dtf)
{
  const int f32 = *dtf;
  const int row = row_base + blockIdx.x;
  const int b = row >> 9, c = row & 511;
  const int tid = threadIdx.x;
  __shared__ float yr[512];
  for (int i = tid; i < 512; i += 128) yr[i] = y[(size_t)blockIdx.x * 512 + i];
  __syncthreads();
  if (tid < PRED) {
    float a = 0.f;
    for (int d = 0; d < 512; ++d) a += yr[d] * lin(fc_w, d * PRED + tid, f32);
    a += lin(fc_b, tid, f32);
    const float r = a * stdb[row] + meanb[row];
    const size_t oi = ((size_t)b * PRED + tid) * CC + c;
    if (f32) ((float*)out)[oi] = r;
    else     ((ushort*)out)[oi] = f2b(r);
  }
}

// ---------------------------------------------------------------------------
extern "C" void kernel_launch(void* const* d_in, const int* in_sizes, int n_in,
                              void* d_out, int out_size, void* d_ws, size_t ws_size,
                              hipStream_t stream)
{
  (void)in_sizes; (void)n_in; (void)out_size;
  const void* x_enc   = d_in[0];
  const void* embed_w = d_in[4];
  const void* q_w = d_in[5],  * q_b = d_in[6];
  const void* k_w = d_in[7],  * k_b = d_in[8];
  const void* v_w = d_in[9],  * v_b = d_in[10];
  const void* o_w = d_in[11], * o_b = d_in[12];
  const void* enc_w = d_in[13], * enc_b = d_in[14];
  const void* f1q_w = d_in[15], * f1q_b = d_in[16];
  const void* f1k_w = d_in[17], * f1k_b = d_in[18];
  const void* f1v_w = d_in[19], * f1v_b = d_in[20];
  const void* f1o_w = d_in[21], * f1o_b = d_in[22];
  const void* f2q_w = d_in[23], * f2q_b = d_in[24];
  const void* f2k_w = d_in[25], * f2k_b = d_in[26];
  const void* f2v_w = d_in[27], * f2v_b = d_in[28];
  const void* f2o_w = d_in[29], * f2o_b = d_in[30];
  const void* ln_g  = d_in[31], * ln_b  = d_in[32];
  const void* fc_w  = d_in[33], * fc_b  = d_in[34];

  const size_t HDR = 131072 + 1024;
  const size_t E_F1Q = 512ull * 2048, E_F1O = 2048ull * 2048, E_F2Q = 2048ull * 512;
  const size_t E_F2K = 2048ull * 2048, E_F2V = 2048ull * 2048, E_F2O = 512ull * 512;
  const size_t E_SQ  = 512ull * 512;   // o_w, enc_w, f1k_w, f1v_w each
  const size_t WT_EL = E_F1Q + E_F1O + E_F2Q + E_F2K + E_F2V + E_F2O + 4 * E_SQ;
  const size_t WT_BYTES = WT_EL * 2;   // ~30.5 MB
  const size_t PER_BATCH = 5ull * 512 * 512 * 4 + 3ull * 512 * DFF * 2; // 11.53MB

  const int use_mfma = (HDR + WT_BYTES + PER_BATCH <= ws_size) ? 1 : 0;
  const size_t FIXED = HDR + (use_mfma ? WT_BYTES : 0);
  int BPC = 1;
  for (int c = 8; c >= 1; c >>= 1) {
    if (FIXED + (size_t)c * PER_BATCH <= ws_size) { BPC = c; break; }
  }
  const int R = BPC * 512;

  char* ws = (char*)d_ws;
  float* meanb = (float*)ws;
  float* stdb  = (float*)(ws + 65536);
  int*   dtf   = (int*)(ws + 131072);
  ushort* wt_base = (ushort*)(ws + HDR);
  ushort* wt_f1q = wt_base;
  ushort* wt_f1o = wt_f1q + E_F1Q;
  ushort* wt_f2q = wt_f1o + E_F1O;
  ushort* wt_f2k = wt_f2q + E_F2Q;
  ushort* wt_f2v = wt_f2k + E_F2K;
  ushort* wt_f2o = wt_f2v + E_F2V;
  ushort* wt_o   = wt_f2o + E_F2O;
  ushort* wt_enc = wt_o   + E_SQ;
  ushort* wt_f1k = wt_enc + E_SQ;
  ushort* wt_f1v = wt_f1k + E_SQ;
  char* arena = ws + FIXED;
  const size_t FSL = (size_t)R * 512 * 4;
  const size_t GSL = (size_t)R * DFF * 2;
  void* A_ = arena;
  void* B_ = arena + FSL;
  void* C_ = arena + 2 * FSL;
  void* D_ = arena + 3 * FSL;
  void* E_ = arena + 4 * FSL;
  void* G1 = arena + 5 * FSL;
  void* G2 = arena + 5 * FSL + GSL;
  void* G3 = arena + 5 * FSL + 2 * GSL;

  detect_dtype<<<1, 256, 0, stream>>>((const ushort*)x_enc, dtf);
  instnorm_stats<<<dim3(2, NB), 256, 0, stream>>>(x_enc, meanb, stdb, dtf);

  if (use_mfma) {   // one-time weight convert+transpose (KxN -> bf16 NxK)
    transpose_w<<<dim3(DFF / 32, 512 / 32), 256, 0, stream>>>(f1q_w, wt_f1q, 512, DFF, dtf);
    transpose_w<<<dim3(DFF / 32, DFF / 32), 256, 0, stream>>>(f1o_w, wt_f1o, DFF, DFF, dtf);
    transpose_w<<<dim3(512 / 32, DFF / 32), 256, 0, stream>>>(f2q_w, wt_f2q, DFF, 512, dtf);
    transpose_w<<<dim3(DFF / 32, DFF / 32), 256, 0, stream>>>(f2k_w, wt_f2k, DFF, DFF, dtf);
    transpose_w<<<dim3(DFF / 32, DFF / 32), 256, 0, stream>>>(f2v_w, wt_f2v, DFF, DFF, dtf);
    transpose_w<<<dim3(512 / 32, 512 / 32), 256, 0, stream>>>(f2o_w, wt_f2o, 512, 512, dtf);
    transpose_w<<<dim3(512 / 32, 512 / 32), 256, 0, stream>>>(o_w,   wt_o,   512, 512, dtf);
    transpose_w<<<dim3(512 / 32, 512 / 32), 256, 0, stream>>>(enc_w, wt_enc, 512, 512, dtf);
    transpose_w<<<dim3(512 / 32, 512 / 32), 256, 0, stream>>>(f1k_w, wt_f1k, 512, 512, dtf);
    transpose_w<<<dim3(512 / 32, 512 / 32), 256, 0, stream>>>(f1v_w, wt_f1v, 512, 512, dtf);
  }

  for (int bc = 0; bc < NB / BPC; ++bc) {
    const int b0 = bc * BPC;
    // --- stage 1 (fp32: feeds top-k mask) ---
    norm_transpose<<<dim3(16, 16, BPC), 256, 0, stream>>>(x_enc, meanb, stdb, (float*)A_, b0, dtf);
    launch_gemm<float, float, float, M_RELU_PE >(A_, embed_w, nullptr, nullptr, B_, R, 512, 512, dtf, stream); // emb
    launch_gemm<float, float, float, M_BIAS_RELU>(B_, q_w, q_b, nullptr, C_, R, 512, 512, dtf, stream);        // q
    launch_gemm<float, float, float, M_BIAS     >(B_, k_w, k_b, nullptr, D_, R, 512, 512, dtf, stream);        // k
    launch_gemm<float, float, float, M_BIAS_RELU>(B_, v_w, v_b, nullptr, E_, R, 512, 512, dtf, stream);        // v

    if (use_mfma) {
      gattn_mfma<<<dim3(CC / 16, HH, BPC), 256, 0, stream>>>(
          (float*)C_, (float*)D_, (float*)E_, (ushort*)A_);                                          // attn bf16
      launch_mgemm<float, ushort, M_ADD_BIAS_LEAKY>(A_, wt_o, o_b, B_, C_, R, 512, 512, dtf, stream); // y bf16
      launch_mgemm<float, ushort, M_BIAS>(C_, wt_enc, enc_b, nullptr, D_, R, 512, 512, dtf, stream);  // X1 bf16
      // --- stage 2: pwattn1 + LN ---
      launch_mgemm<float, ushort, M_BIAS_RELU>(D_, wt_f1q, f1q_b, nullptr, G1, R, 512, DFF, dtf, stream); // query1
      launch_mgemm<float, float,  M_BIAS     >(D_, wt_f1k, f1k_b, nullptr, A_, R, 512, 512, dtf, stream); // k1 f32
      launch_mgemm<float, float,  M_BIAS_RELU>(D_, wt_f1v, f1v_b, nullptr, B_, R, 512, 512, dtf, stream); // v1 f32
      pwattn1_kernel<<<R, 128, 0, stream>>>((const ushort*)G1, (const float*)A_, (const float*)B_, (ushort*)G2);
      launch_mgemm<ushort, ushort, M_ADD_BIAS_ELU>(G2, wt_f1o, f1o_b, G1, G1, R, DFF, DFF, dtf, stream);  // h
      ln_kernel<<<R, 256, 0, stream>>>((ushort*)G1, ln_g, ln_b, dtf);
      // --- stage 3: pwattn2 + out ---
      launch_mgemm<float, float,  M_BIAS_RELU>(G1, wt_f2q, f2q_b, nullptr, A_, R, DFF, 512, dtf, stream); // query2
      launch_mgemm<float, ushort, M_BIAS     >(G1, wt_f2k, f2k_b, nullptr, G2, R, DFF, DFF, dtf, stream); // k2
      launch_mgemm<float, ushort, M_BIAS_RELU>(G1, wt_f2v, f2v_b, nullptr, G3, R, DFF, DFF, dtf, stream); // v2
      pwattn2_kernel<ushort><<<R, 128, 0, stream>>>((const float*)A_, (const ushort*)G2, (const ushort*)G3, (ushort*)B_);
      launch_mgemm<float, float, M_ADD_BIAS>(B_, wt_f2o, f2o_b, A_, C_, R, 512, 512, dtf, stream);        // y2
    } else {
      gattn_fb<float><<<dim3(CC / 4, HH, BPC), 256, 0, stream>>>(
          (float*)C_, (float*)D_, (float*)E_, (float*)A_);
      launch_gemm<float, float, float, M_ADD_BIAS_LEAKY>(A_, o_w, o_b, B_, C_, R, 512, 512, dtf, stream);
      launch_gemm<float, float, float, M_BIAS>(C_, enc_w, enc_b, nullptr, D_, R, 512, 512, dtf, stream);
      launch_gemm<float, float, ushort, M_BIAS_RELU>(D_, f1q_w, f1q_b, nullptr, G1, R, 512, DFF, dtf, stream);
      launch_gemm<float, float, float,  M_BIAS     >(D_, f1k_w, f1k_b, nullptr, A_, R, 512, 512, dtf, stream);
      launch_gemm<float, float, float,  M_BIAS_RELU>(D_, f1v_w, f1v_b, nullptr, B_, R, 512, 512, dtf, stream);
      pwattn1_kernel<<<R, 128, 0, stream>>>((const ushort*)G1, (const float*)A_, (const float*)B_, (ushort*)G2);
      launch_gemm<ushort, ushort, ushort, M_ADD_BIAS_ELU>(G2, f1o_w, f1o_b, G1, G1, R, DFF, DFF, dtf, stream);
      ln_kernel<<<R, 256, 0, stream>>>((ushort*)G1, ln_g, ln_b, dtf);
      launch_gemm<ushort, float, float,  M_BIAS_RELU>(G1, f2q_w, f2q_b, nullptr, A_, R, DFF, 512, dtf, stream);
      launch_gemm<ushort, float, ushort, M_BIAS     >(G1, f2k_w, f2k_b, nullptr, G2, R, DFF, DFF, dtf, stream);
      launch_gemm<ushort, float, ushort, M_BIAS_RELU>(G1, f2v_w, f2v_b, nullptr, G3, R, DFF, DFF, dtf, stream);
      pwattn2_kernel<float><<<R, 128, 0, stream>>>((const float*)A_, (const ushort*)G2, (const ushort*)G3, (float*)B_);
      launch_gemm<float, float, float, M_ADD_BIAS>(B_, f2o_w, f2o_b, A_, C_, R, 512, 512, dtf, stream);
    }
    final_kernel<<<R, 128, 0, stream>>>((const float*)C_, fc_w, fc_b, meanb, stdb, d_out, b0 * 512, dtf);
  }
}